// Round 1
// baseline (1225.601 us; speedup 1.0000x reference)
//
#include <hip/hip_runtime.h>
#include <hip/hip_bf16.h>
#include <math.h>

// Problem constants (B=1)
#define LL_ 256   // L
#define MM_ 512   // M
#define AA_ 21    // A
#define CC_ 20    // A-1
#define KK_ (LL_*AA_)  // 5376
#define SIM_K 10.0f
#define SIM_MID 0.8f

// Workspace layout (floats)
#define OFF_MSAK   ((size_t)0)          // [K][M] = 2752512
#define OFF_HC     ((size_t)2752512)    // [M][L][A] = 2752512
#define OFF_LOGP   ((size_t)5505024)    // [L][M] = 131072
#define OFF_S      ((size_t)5636096)    // [M][M] = 262144
#define OFF_DENOM  ((size_t)5898240)    // [M]
#define OFF_LWSUM  ((size_t)5898752)    // [1]

// ---------------- K0: transpose MSA (b,l,m,a) -> msa_k[(l*A+a)][m] ----------
__global__ __launch_bounds__(256) void k0_transpose(const float* __restrict__ MSA,
                                                    float* __restrict__ msa_k) {
    const int l = blockIdx.x;
    const int m = blockIdx.y * 256 + threadIdx.x;
    const float* src = MSA + ((size_t)l * MM_ + m) * AA_;
#pragma unroll
    for (int a = 0; a < AA_; ++a) {
        msa_k[(size_t)(l * AA_ + a) * MM_ + m] = src[a];
    }
}

// ---------------- K_lw: sum(length_weight) ---------------------------------
__global__ __launch_bounds__(256) void k_lwsum(const float* __restrict__ lw,
                                               float* __restrict__ out) {
    const int t = threadIdx.x;
    float v = lw[t];
#pragma unroll
    for (int off = 32; off; off >>= 1) v += __shfl_down(v, off, 64);
    __shared__ float r[4];
    if ((t & 63) == 0) r[t >> 6] = v;
    __syncthreads();
    if (t == 0) out[0] = r[0] + r[1] + r[2] + r[3];
}

// ---------------- K1: H_edge_mut GEMM --------------------------------------
// out[m, l, c] = sum_{p,a} msa_k[(p*A+a)][m] * J[l, p, c, a]
// Block: 4 l's x 128 m's, 512 threads. Thread tile: 4m x 6n (n=(ll,c), 84 n's).
#define K1_BL 4
#define K1_BM 128
#define K1_PP 4
__global__ __launch_bounds__(512) void k1_edge(const float* __restrict__ Jg,
                                               const float* __restrict__ msa_k,
                                               float* __restrict__ Hc) {
    const int m0 = blockIdx.x * K1_BM;
    const int l0 = blockIdx.y * K1_BL;
    const int tid = threadIdx.x;
    const int mq = tid & 31;   // 32 groups of 4 m
    const int nq = tid >> 5;   // 16 groups over 84 n (n = nq + 16*j)
    // [pp][a][n] ; n padded 84 -> 96 so the 6th j-slot reads in-bounds garbage
    __shared__ float Jl[K1_PP][AA_][96];
    float acc[6][4];
#pragma unroll
    for (int j = 0; j < 6; ++j)
#pragma unroll
        for (int i = 0; i < 4; ++i) acc[j][i] = 0.f;

    const int nj = (nq < 4) ? 6 : 5;  // valid n count for this thread

    for (int p0 = 0; p0 < LL_; p0 += K1_PP) {
        __syncthreads();
        // stage J[l0..l0+3][p0..p0+3][:][:] -> Jl[pp][a][ll*21+c]
        for (int idx = tid; idx < K1_BL * K1_PP * 441; idx += 512) {
            const int pair = idx / 441;          // (ll,pp)
            const int f = idx - pair * 441;      // c*21+a
            const int ll = pair >> 2;
            const int pp = pair & 3;
            const int c = f / 21;
            const int a = f - c * 21;
            Jl[pp][a][ll * 21 + c] =
                Jg[(size_t)(l0 + ll) * (LL_ * AA_ * AA_) + (size_t)(p0 + pp) * 441 + f];
        }
        __syncthreads();
#pragma unroll
        for (int pp = 0; pp < K1_PP; ++pp) {
#pragma unroll 7
            for (int a = 0; a < AA_; ++a) {
                const int k = (p0 + pp) * AA_ + a;
                const float4 av =
                    *(const float4*)(msa_k + (size_t)k * MM_ + m0 + (mq << 2));
#pragma unroll
                for (int j = 0; j < 6; ++j) {
                    const float b = Jl[pp][a][nq + 16 * j];
                    acc[j][0] = fmaf(av.x, b, acc[j][0]);
                    acc[j][1] = fmaf(av.y, b, acc[j][1]);
                    acc[j][2] = fmaf(av.z, b, acc[j][2]);
                    acc[j][3] = fmaf(av.w, b, acc[j][3]);
                }
            }
        }
    }
    // writeback: Hc[m][l][c]
    for (int j = 0; j < nj; ++j) {
        const int n = nq + 16 * j;
        const int ll = n / 21;
        const int c = n - ll * 21;
        const int l = l0 + ll;
#pragma unroll
        for (int i = 0; i < 4; ++i) {
            const int m = m0 + (mq << 2) + i;
            Hc[((size_t)m * LL_ + l) * AA_ + c] = acc[j][i];
        }
    }
}

// ---------------- K2: node terms + log-softmax + logp_msa + H_out ----------
__global__ __launch_bounds__(512) void k2_node(const float* __restrict__ MSA,
                                               const float* __restrict__ hvec,
                                               const float* __restrict__ Hc,
                                               float* __restrict__ logp,
                                               float* __restrict__ out) {
    const int l = blockIdx.x;
    const int m = threadIdx.x;  // 512
    __shared__ float hl[AA_];
    if (m < AA_) hl[m] = hvec[l * AA_ + m];
    __syncthreads();

    const float* msa = MSA + ((size_t)l * MM_ + m) * AA_;
    const float* hc = Hc + ((size_t)m * LL_ + l) * AA_;
    float msav[AA_], hcv[AA_];
#pragma unroll
    for (int a = 0; a < AA_; ++a) { msav[a] = msa[a]; hcv[a] = hc[a]; }

    float nodewt = 0.f, edgewt = 0.f;
#pragma unroll
    for (int a = 0; a < AA_; ++a) {
        nodewt = fmaf(msav[a], hl[a], nodewt);
        edgewt = fmaf(msav[a], hcv[a], edgewt);
    }
    float hd[CC_];
    float mx = -1e30f;
#pragma unroll
    for (int c = 0; c < CC_; ++c) {
        hd[c] = (hl[c] - nodewt) + (hcv[c] - edgewt);
        mx = fmaxf(mx, -hd[c]);
    }
    float s = 0.f;
#pragma unroll
    for (int c = 0; c < CC_; ++c) s += expf(-hd[c] - mx);
    const float lse = mx + logf(s);
    float lpsum = 0.f;
#pragma unroll
    for (int c = 0; c < CC_; ++c) lpsum = fmaf(-hd[c] - lse, msav[c], lpsum);
    logp[l * MM_ + m] = lpsum;

    if (m == 0) {  // REF_SPECIES_INDEX = 0
#pragma unroll
        for (int c = 0; c < CC_; ++c) out[l * CC_ + c] = hd[c];
    }
}

// ---------------- K3: similarity GEMM (lw folded into B side) --------------
// S[m][n] = sum_{l,a} msa[m,l,a]*msa[n,l,a]*lw[l]  (split-K over l, atomics)
__global__ __launch_bounds__(256) void k3_sim(const float* __restrict__ msa_k,
                                              const float* __restrict__ lw,
                                              float* __restrict__ S) {
    const int m0 = blockIdx.x * 64;
    const int n0 = blockIdx.y * 64;
    const int l0 = blockIdx.z * 32;
    const int tid = threadIdx.x;
    const int tx = tid & 15;   // m group (4 each)
    const int ty = tid >> 4;   // n group (4 each)
    __shared__ __align__(16) float As[21][64];
    __shared__ __align__(16) float Bs[21][64];
    float acc[4][4];
#pragma unroll
    for (int i = 0; i < 4; ++i)
#pragma unroll
        for (int j = 0; j < 4; ++j) acc[i][j] = 0.f;

    for (int l = l0; l < l0 + 32; ++l) {
        __syncthreads();
        const float lwv = lw[l];
        for (int idx = tid; idx < 21 * 64; idx += 256) {
            const int kk = idx >> 6, mm = idx & 63;
            const size_t row = (size_t)(l * 21 + kk) * MM_;
            As[kk][mm] = msa_k[row + m0 + mm];
            Bs[kk][mm] = msa_k[row + n0 + mm] * lwv;
        }
        __syncthreads();
#pragma unroll 7
        for (int kk = 0; kk < 21; ++kk) {
            const float4 a4 = *(const float4*)&As[kk][tx * 4];
            const float4 b4 = *(const float4*)&Bs[kk][ty * 4];
            const float av[4] = {a4.x, a4.y, a4.z, a4.w};
            const float bv[4] = {b4.x, b4.y, b4.z, b4.w};
#pragma unroll
            for (int i = 0; i < 4; ++i)
#pragma unroll
                for (int j = 0; j < 4; ++j)
                    acc[i][j] = fmaf(av[i], bv[j], acc[i][j]);
        }
    }
#pragma unroll
    for (int i = 0; i < 4; ++i)
#pragma unroll
        for (int j = 0; j < 4; ++j)
            atomicAdd(&S[(size_t)(m0 + tx * 4 + i) * MM_ + n0 + ty * 4 + j],
                      acc[i][j]);
}

// ---------------- K4: denom[m] = sum_n sigmoid(K*(sim-mid)) ----------------
__global__ __launch_bounds__(64) void k4_denom(const float* __restrict__ S,
                                               const float* __restrict__ lwsum_p,
                                               float* __restrict__ denom) {
    const int m = blockIdx.x * 64 + threadIdx.x;
    const float inv = 1.0f / lwsum_p[0];
    float s = 0.f;
    for (int n = 0; n < MM_; ++n) {
        // S is symmetric: read column m (coalesced across threads)
        const float sim = S[(size_t)n * MM_ + m] * inv;
        s += 1.0f / (1.0f + expf(-SIM_K * (sim - SIM_MID)));
    }
    denom[m] = s;
}

// ---------------- K5: final weighted scalar --------------------------------
__global__ __launch_bounds__(512) void k5_final(const float* __restrict__ logp,
                                                const float* __restrict__ lw,
                                                const float* __restrict__ denom,
                                                const float* __restrict__ dw,
                                                float* __restrict__ out) {
    const int m = threadIdx.x;  // 512
    float lp = 0.f;
    for (int l = 0; l < LL_; ++l) lp = fmaf(logp[l * MM_ + m], lw[l], lp);
    const float sw = dw[m] / denom[m];
    float a = sw * lp, b = sw;
#pragma unroll
    for (int off = 32; off; off >>= 1) {
        a += __shfl_down(a, off, 64);
        b += __shfl_down(b, off, 64);
    }
    __shared__ float ra[8], rb[8];
    if ((m & 63) == 0) { ra[m >> 6] = a; rb[m >> 6] = b; }
    __syncthreads();
    if (m == 0) {
        float sa = 0.f, sb = 0.f;
#pragma unroll
        for (int w = 0; w < 8; ++w) { sa += ra[w]; sb += rb[w]; }
        out[5120] = sa / sb;
    }
}

extern "C" void kernel_launch(void* const* d_in, const int* in_sizes, int n_in,
                              void* d_out, int out_size, void* d_ws, size_t ws_size,
                              hipStream_t stream) {
    const float* MSA = (const float*)d_in[0];   // (1,256,512,21)
    const float* h   = (const float*)d_in[1];   // (1,256,21)
    const float* J   = (const float*)d_in[2];   // (1,256,256,21,21)
    const float* lw  = (const float*)d_in[3];   // (1,256,1)
    const float* dw  = (const float*)d_in[4];   // (1,512)
    float* out = (float*)d_out;                 // 5121 floats
    float* ws = (float*)d_ws;

    float* msa_k = ws + OFF_MSAK;
    float* Hc    = ws + OFF_HC;
    float* logp  = ws + OFF_LOGP;
    float* S     = ws + OFF_S;
    float* denom = ws + OFF_DENOM;
    float* lwsum = ws + OFF_LWSUM;

    // K0: transpose
    k0_transpose<<<dim3(LL_, MM_ / 256), 256, 0, stream>>>(MSA, msa_k);
    // lwsum
    k_lwsum<<<1, 256, 0, stream>>>(lw, lwsum);
    // zero S (ws is poisoned each call)
    hipMemsetAsync(S, 0, (size_t)MM_ * MM_ * sizeof(float), stream);
    // K1: edge GEMM (the heavy one)
    k1_edge<<<dim3(MM_ / K1_BM, LL_ / K1_BL), 512, 0, stream>>>(J, msa_k, Hc);
    // K3: similarity GEMM (independent of K1, runs after it on stream)
    k3_sim<<<dim3(8, 8, 8), 256, 0, stream>>>(msa_k, lw, S);
    // K2: per-(m,l) softmax + logp_msa + H_out
    k2_node<<<dim3(LL_), 512, 0, stream>>>(MSA, h, Hc, logp, out);
    // K4: sigmoid row sums
    k4_denom<<<dim3(MM_ / 64), 64, 0, stream>>>(S, lwsum, denom);
    // K5: final scalar
    k5_final<<<1, 512, 0, stream>>>(logp, lw, denom, dw, out);
}

// Round 7
// 855.237 us; speedup vs baseline: 1.4331x; 1.4331x over previous
//
#include <hip/hip_runtime.h>
#include <hip/hip_bf16.h>
#include <math.h>

// Problem constants (B=1)
#define LL_ 256   // L
#define MM_ 512   // M
#define AA_ 21    // A
#define CC_ 20    // A-1
#define KK_ (LL_*AA_)  // 5376
#define SIM_K 10.0f
#define SIM_MID 0.8f

typedef __attribute__((ext_vector_type(8))) short bf16x8;
typedef __attribute__((ext_vector_type(4))) float f32x4;
#define MFMA16 __builtin_amdgcn_mfma_f32_16x16x32_bf16

static __device__ __forceinline__ unsigned short f2bf(float x) {
    union { float f; unsigned u; } v; v.f = x;
    unsigned r = v.u + 0x7fffu + ((v.u >> 16) & 1u);
    return (unsigned short)(r >> 16);
}
static __device__ __forceinline__ float bf2f(unsigned short h) {
    union { unsigned u; float f; } v; v.u = ((unsigned)h) << 16; return v.f;
}

// ====================== NEW MFMA PATH =====================================
// ws byte offsets
#define B_JTHI  ((size_t)0)            // ushort[5376][5376]
#define B_JTLO  ((size_t)57802752)
#define B_AH    ((size_t)115605504)    // ushort[512][5376]
#define B_AL    ((size_t)121110528)
#define B_HC    ((size_t)126615552)    // float[512][5376]
#define B_MSAK  ((size_t)137625600)    // float[5376][512]
#define B_LOGP  ((size_t)148635648)    // float[256][512]
#define B_S     ((size_t)149159936)    // float[512][512]
#define B_DENOM ((size_t)150208512)    // float[512]
#define B_LWSUM ((size_t)150210560)    // float[1]
#define WS_NEED ((size_t)150210564)

// --- kT: J[l,p,c,a] (fp32) -> Jt_hi/lo[(l*21+c)][(p*21+a)] bf16 ------------
__global__ __launch_bounds__(256) void kT_jt(const float* __restrict__ J,
                                             unsigned short* __restrict__ Jt_hi,
                                             unsigned short* __restrict__ Jt_lo) {
    const int l = blockIdx.x;
    const int p0 = blockIdx.y * 32;
    const int tid = threadIdx.x;
    __shared__ float slab[32 * 441];  // 56.4 KB
    const float* Jb = J + ((size_t)l * 256 + p0) * 441;
    for (int i = tid; i < 32 * 441; i += 256) slab[i] = Jb[i];
    __syncthreads();
    // output granules: 21 rows (c) x 84 16B-granules (8 k each)
    for (int s = tid; s < 21 * 84; s += 256) {
        const int c = s / 84;
        const int kk8 = s - c * 84;
        bf16x8 hv, lv;
#pragma unroll
        for (int j = 0; j < 8; ++j) {
            const int kseg = kk8 * 8 + j;        // 0..671
            const int pl = kseg / 21;
            const int a = kseg - pl * 21;
            const float x = slab[pl * 441 + c * 21 + a];
            const unsigned short h = f2bf(x);
            hv[j] = (short)h;
            lv[j] = (short)f2bf(x - bf2f(h));
        }
        const size_t row = (size_t)(l * 21 + c);
        const size_t off = row * KK_ + p0 * 21 + kk8 * 8;
        *(bf16x8*)(Jt_hi + off) = hv;
        *(bf16x8*)(Jt_lo + off) = lv;
    }
}

// --- kA: MSA[p,m,a] -> Ah/Al[m][(p*21+a)] bf16 -----------------------------
__global__ __launch_bounds__(512) void kA_msa(const float* __restrict__ MSA,
                                              unsigned short* __restrict__ Ah,
                                              unsigned short* __restrict__ Al) {
    const int p0 = blockIdx.x * 8;
    const int m0 = blockIdx.y * 64;
    const int tid = threadIdx.x;
    __shared__ float slab[8 * 64 * 21];  // 43 KB : [pl][ml][a]
    for (int pl = 0; pl < 8; ++pl) {
        const float* src = MSA + ((size_t)(p0 + pl) * MM_ + m0) * AA_;
        for (int i = tid; i < 64 * 21; i += 512) slab[pl * 1344 + i] = src[i];
    }
    __syncthreads();
    const int ml = tid >> 3;
    const int pl = tid & 7;
    const size_t rowb = (size_t)(m0 + ml) * KK_ + (size_t)(p0 + pl) * 21;
#pragma unroll
    for (int a = 0; a < AA_; ++a) {
        const float x = slab[pl * 1344 + ml * 21 + a];
        const unsigned short h = f2bf(x);
        Ah[rowb + a] = h;
        Al[rowb + a] = f2bf(x - bf2f(h));
    }
}

// --- k1_mfma: Hc[m][n] = sum_k A[m][k] * Jt[n][k], 3-term bf16 split -------
// grid (4, 64): m0 = bx*128, lg = by (4 l's = 84 valid n). 512 threads.
#define K1M_AROW 136   // ushort per LDS row: 64 hi + 64 lo + 8 pad
__global__ __launch_bounds__(512) void k1_mfma(const unsigned short* __restrict__ Jt_hi,
                                               const unsigned short* __restrict__ Jt_lo,
                                               const unsigned short* __restrict__ Ah,
                                               const unsigned short* __restrict__ Al,
                                               float* __restrict__ Hc) {
    const int m0 = blockIdx.x * 128;
    const int lg = blockIdx.y;
    const int tid = threadIdx.x;
    const int lane = tid & 63;
    const int w = tid >> 6;
    const int wm = w >> 1;          // 0..3
    const int wn = w & 1;           // 0..1
    const int lr = lane & 15;
    const int lgk = lane >> 4;      // 0..3

    __shared__ unsigned short lds[(128 + 96) * K1M_AROW];  // 60.9 KB
    const int BOFF = 128 * K1M_AROW;

    // staging: 3584 granules of 16B = 7 per thread
    const unsigned short* sp[7];
    int dp[7];
#pragma unroll
    for (int i = 0; i < 7; ++i) {
        const int gid = tid + i * 512;
        if (gid < 2048) {  // A
            const int row = gid >> 4;
            const int g = gid & 15;
            const int pl = g >> 3;
            const int gg = g & 7;
            sp[i] = (pl ? Al : Ah) + (size_t)(m0 + row) * KK_ + gg * 8;
            dp[i] = row * K1M_AROW + pl * 64 + gg * 8;
        } else {           // B
            const int b = gid - 2048;
            const int row = b >> 4;
            const int g = b & 15;
            const int pl = g >> 3;
            const int gg = g & 7;
            int srow = lg * 84 + row; if (srow > 5375) srow = 5375;
            sp[i] = (pl ? Jt_lo : Jt_hi) + (size_t)srow * KK_ + gg * 8;
            dp[i] = BOFF + row * K1M_AROW + pl * 64 + gg * 8;
        }
    }

    f32x4 acc[2][3];
#pragma unroll
    for (int ms = 0; ms < 2; ++ms)
#pragma unroll
        for (int ns = 0; ns < 3; ++ns) acc[ms][ns] = (f32x4)(0.f);

    int4 r[7];
#pragma unroll
    for (int i = 0; i < 7; ++i) r[i] = *(const int4*)(sp[i]);

    for (int t = 0; t < 84; ++t) {
#pragma unroll
        for (int i = 0; i < 7; ++i) *(int4*)&lds[dp[i]] = r[i];
        __syncthreads();
        if (t < 83) {
            const size_t koff = (size_t)(t + 1) * 64;
#pragma unroll
            for (int i = 0; i < 7; ++i) r[i] = *(const int4*)(sp[i] + koff);
        }
#pragma unroll
        for (int kc = 0; kc < 2; ++kc) {
            bf16x8 a_h[2], a_l[2], b_h[3], b_l[3];
            const int kb = kc * 32 + lgk * 8;
#pragma unroll
            for (int ms = 0; ms < 2; ++ms) {
                const unsigned short* p = &lds[(wm * 32 + ms * 16 + lr) * K1M_AROW + kb];
                a_h[ms] = *(const bf16x8*)p;
                a_l[ms] = *(const bf16x8*)(p + 64);
            }
#pragma unroll
            for (int ns = 0; ns < 3; ++ns) {
                const unsigned short* p = &lds[BOFF + (wn * 48 + ns * 16 + lr) * K1M_AROW + kb];
                b_h[ns] = *(const bf16x8*)p;
                b_l[ns] = *(const bf16x8*)(p + 64);
            }
#pragma unroll
            for (int ms = 0; ms < 2; ++ms)
#pragma unroll
                for (int ns = 0; ns < 3; ++ns) {
                    acc[ms][ns] = MFMA16(a_h[ms], b_h[ns], acc[ms][ns], 0, 0, 0);
                    acc[ms][ns] = MFMA16(a_h[ms], b_l[ns], acc[ms][ns], 0, 0, 0);
                    acc[ms][ns] = MFMA16(a_l[ms], b_h[ns], acc[ms][ns], 0, 0, 0);
                }
        }
        __syncthreads();
    }
    // writeback: C row = (lane>>4)*4 + reg (m), col = lane&15 (n)  [m89]
#pragma unroll
    for (int ms = 0; ms < 2; ++ms)
#pragma unroll
        for (int ns = 0; ns < 3; ++ns) {
            const int nloc = wn * 48 + ns * 16 + lr;
            if (nloc < 84) {
                const size_t ng = (size_t)lg * 84 + nloc;
#pragma unroll
                for (int rr = 0; rr < 4; ++rr) {
                    const int m = m0 + wm * 32 + ms * 16 + lgk * 4 + rr;
                    Hc[(size_t)m * KK_ + ng] = acc[ms][ns][rr];
                }
            }
        }
}

// ====================== SHARED / OLD PATH KERNELS ==========================
// old-path ws offsets (floats)
#define OFF_MSAK   ((size_t)0)
#define OFF_HC     ((size_t)2752512)
#define OFF_LOGP   ((size_t)5505024)
#define OFF_S      ((size_t)5636096)
#define OFF_DENOM  ((size_t)5898240)
#define OFF_LWSUM  ((size_t)5898752)

__global__ __launch_bounds__(256) void k0_transpose(const float* __restrict__ MSA,
                                                    float* __restrict__ msa_k) {
    const int l = blockIdx.x;
    const int m = blockIdx.y * 256 + threadIdx.x;
    const float* src = MSA + ((size_t)l * MM_ + m) * AA_;
#pragma unroll
    for (int a = 0; a < AA_; ++a) msa_k[(size_t)(l * AA_ + a) * MM_ + m] = src[a];
}

__global__ __launch_bounds__(256) void k_lwsum(const float* __restrict__ lw,
                                               float* __restrict__ out) {
    const int t = threadIdx.x;
    float v = lw[t];
#pragma unroll
    for (int off = 32; off; off >>= 1) v += __shfl_down(v, off, 64);
    __shared__ float r[4];
    if ((t & 63) == 0) r[t >> 6] = v;
    __syncthreads();
    if (t == 0) out[0] = r[0] + r[1] + r[2] + r[3];
}

// old fp32 VALU edge GEMM (fallback only)
#define K1_BL 4
#define K1_BM 128
#define K1_PP 4
__global__ __launch_bounds__(512) void k1_edge(const float* __restrict__ Jg,
                                               const float* __restrict__ msa_k,
                                               float* __restrict__ Hc) {
    const int m0 = blockIdx.x * K1_BM;
    const int l0 = blockIdx.y * K1_BL;
    const int tid = threadIdx.x;
    const int mq = tid & 31;
    const int nq = tid >> 5;
    __shared__ float Jl[K1_PP][AA_][96];
    float acc[6][4];
#pragma unroll
    for (int j = 0; j < 6; ++j)
#pragma unroll
        for (int i = 0; i < 4; ++i) acc[j][i] = 0.f;
    const int nj = (nq < 4) ? 6 : 5;
    for (int p0 = 0; p0 < LL_; p0 += K1_PP) {
        __syncthreads();
        for (int idx = tid; idx < K1_BL * K1_PP * 441; idx += 512) {
            const int pair = idx / 441;
            const int f = idx - pair * 441;
            const int ll = pair >> 2;
            const int pp = pair & 3;
            const int c = f / 21;
            const int a = f - c * 21;
            Jl[pp][a][ll * 21 + c] =
                Jg[(size_t)(l0 + ll) * (LL_ * AA_ * AA_) + (size_t)(p0 + pp) * 441 + f];
        }
        __syncthreads();
#pragma unroll
        for (int pp = 0; pp < K1_PP; ++pp) {
#pragma unroll 7
            for (int a = 0; a < AA_; ++a) {
                const int k = (p0 + pp) * AA_ + a;
                const float4 av = *(const float4*)(msa_k + (size_t)k * MM_ + m0 + (mq << 2));
#pragma unroll
                for (int j = 0; j < 6; ++j) {
                    const float b = Jl[pp][a][nq + 16 * j];
                    acc[j][0] = fmaf(av.x, b, acc[j][0]);
                    acc[j][1] = fmaf(av.y, b, acc[j][1]);
                    acc[j][2] = fmaf(av.z, b, acc[j][2]);
                    acc[j][3] = fmaf(av.w, b, acc[j][3]);
                }
            }
        }
    }
    for (int j = 0; j < nj; ++j) {
        const int n = nq + 16 * j;
        const int ll = n / 21;
        const int c = n - ll * 21;
        const int l = l0 + ll;
#pragma unroll
        for (int i = 0; i < 4; ++i) {
            const int m = m0 + (mq << 2) + i;
            Hc[((size_t)m * LL_ + l) * AA_ + c] = acc[j][i];
        }
    }
}

__global__ __launch_bounds__(512) void k2_node(const float* __restrict__ MSA,
                                               const float* __restrict__ hvec,
                                               const float* __restrict__ Hc,
                                               float* __restrict__ logp,
                                               float* __restrict__ out) {
    const int l = blockIdx.x;
    const int m = threadIdx.x;
    __shared__ float hl[AA_];
    if (m < AA_) hl[m] = hvec[l * AA_ + m];
    __syncthreads();
    const float* msa = MSA + ((size_t)l * MM_ + m) * AA_;
    const float* hc = Hc + ((size_t)m * LL_ + l) * AA_;
    float msav[AA_], hcv[AA_];
#pragma unroll
    for (int a = 0; a < AA_; ++a) { msav[a] = msa[a]; hcv[a] = hc[a]; }
    float nodewt = 0.f, edgewt = 0.f;
#pragma unroll
    for (int a = 0; a < AA_; ++a) {
        nodewt = fmaf(msav[a], hl[a], nodewt);
        edgewt = fmaf(msav[a], hcv[a], edgewt);
    }
    float hd[CC_];
    float mx = -1e30f;
#pragma unroll
    for (int c = 0; c < CC_; ++c) {
        hd[c] = (hl[c] - nodewt) + (hcv[c] - edgewt);
        mx = fmaxf(mx, -hd[c]);
    }
    float s = 0.f;
#pragma unroll
    for (int c = 0; c < CC_; ++c) s += expf(-hd[c] - mx);
    const float lse = mx + logf(s);
    float lpsum = 0.f;
#pragma unroll
    for (int c = 0; c < CC_; ++c) lpsum = fmaf(-hd[c] - lse, msav[c], lpsum);
    logp[l * MM_ + m] = lpsum;
    if (m == 0) {
#pragma unroll
        for (int c = 0; c < CC_; ++c) out[l * CC_ + c] = hd[c];
    }
}

__global__ __launch_bounds__(256) void k3_sim(const float* __restrict__ msa_k,
                                              const float* __restrict__ lw,
                                              float* __restrict__ S) {
    const int m0 = blockIdx.x * 64;
    const int n0 = blockIdx.y * 64;
    const int l0 = blockIdx.z * 32;
    const int tid = threadIdx.x;
    const int tx = tid & 15;
    const int ty = tid >> 4;
    __shared__ __align__(16) float As[21][64];
    __shared__ __align__(16) float Bs[21][64];
    float acc[4][4];
#pragma unroll
    for (int i = 0; i < 4; ++i)
#pragma unroll
        for (int j = 0; j < 4; ++j) acc[i][j] = 0.f;
    for (int l = l0; l < l0 + 32; ++l) {
        __syncthreads();
        const float lwv = lw[l];
        for (int idx = tid; idx < 21 * 64; idx += 256) {
            const int kk = idx >> 6, mm = idx & 63;
            const size_t row = (size_t)(l * 21 + kk) * MM_;
            As[kk][mm] = msa_k[row + m0 + mm];
            Bs[kk][mm] = msa_k[row + n0 + mm] * lwv;
        }
        __syncthreads();
#pragma unroll 7
        for (int kk = 0; kk < 21; ++kk) {
            const float4 a4 = *(const float4*)&As[kk][tx * 4];
            const float4 b4 = *(const float4*)&Bs[kk][ty * 4];
            const float av[4] = {a4.x, a4.y, a4.z, a4.w};
            const float bv[4] = {b4.x, b4.y, b4.z, b4.w};
#pragma unroll
            for (int i = 0; i < 4; ++i)
#pragma unroll
                for (int j = 0; j < 4; ++j)
                    acc[i][j] = fmaf(av[i], bv[j], acc[i][j]);
        }
    }
#pragma unroll
    for (int i = 0; i < 4; ++i)
#pragma unroll
        for (int j = 0; j < 4; ++j)
            atomicAdd(&S[(size_t)(m0 + tx * 4 + i) * MM_ + n0 + ty * 4 + j], acc[i][j]);
}

__global__ __launch_bounds__(64) void k4_denom(const float* __restrict__ S,
                                               const float* __restrict__ lwsum_p,
                                               float* __restrict__ denom) {
    const int m = blockIdx.x * 64 + threadIdx.x;
    const float inv = 1.0f / lwsum_p[0];
    float s = 0.f;
    for (int n = 0; n < MM_; ++n) {
        const float sim = S[(size_t)n * MM_ + m] * inv;
        s += 1.0f / (1.0f + expf(-SIM_K * (sim - SIM_MID)));
    }
    denom[m] = s;
}

__global__ __launch_bounds__(512) void k5_final(const float* __restrict__ logp,
                                                const float* __restrict__ lw,
                                                const float* __restrict__ denom,
                                                const float* __restrict__ dw,
                                                float* __restrict__ out) {
    const int m = threadIdx.x;
    float lp = 0.f;
    for (int l = 0; l < LL_; ++l) lp = fmaf(logp[l * MM_ + m], lw[l], lp);
    const float sw = dw[m] / denom[m];
    float a = sw * lp, b = sw;
#pragma unroll
    for (int off = 32; off; off >>= 1) {
        a += __shfl_down(a, off, 64);
        b += __shfl_down(b, off, 64);
    }
    __shared__ float ra[8], rb[8];
    if ((m & 63) == 0) { ra[m >> 6] = a; rb[m >> 6] = b; }
    __syncthreads();
    if (m == 0) {
        float sa = 0.f, sb = 0.f;
#pragma unroll
        for (int w = 0; w < 8; ++w) { sa += ra[w]; sb += rb[w]; }
        out[5120] = sa / sb;
    }
}

extern "C" void kernel_launch(void* const* d_in, const int* in_sizes, int n_in,
                              void* d_out, int out_size, void* d_ws, size_t ws_size,
                              hipStream_t stream) {
    const float* MSA = (const float*)d_in[0];
    const float* h   = (const float*)d_in[1];
    const float* J   = (const float*)d_in[2];
    const float* lw  = (const float*)d_in[3];
    const float* dw  = (const float*)d_in[4];
    float* out = (float*)d_out;

    if (ws_size >= WS_NEED) {
        char* wsb = (char*)d_ws;
        unsigned short* Jt_hi = (unsigned short*)(wsb + B_JTHI);
        unsigned short* Jt_lo = (unsigned short*)(wsb + B_JTLO);
        unsigned short* Ah    = (unsigned short*)(wsb + B_AH);
        unsigned short* Al    = (unsigned short*)(wsb + B_AL);
        float* Hc    = (float*)(wsb + B_HC);
        float* msa_k = (float*)(wsb + B_MSAK);
        float* logp  = (float*)(wsb + B_LOGP);
        float* S     = (float*)(wsb + B_S);
        float* denom = (float*)(wsb + B_DENOM);
        float* lwsum = (float*)(wsb + B_LWSUM);

        kT_jt<<<dim3(LL_, 8), 256, 0, stream>>>(J, Jt_hi, Jt_lo);
        kA_msa<<<dim3(32, 8), 512, 0, stream>>>(MSA, Ah, Al);
        k0_transpose<<<dim3(LL_, MM_ / 256), 256, 0, stream>>>(MSA, msa_k);
        k_lwsum<<<1, 256, 0, stream>>>(lw, lwsum);
        hipMemsetAsync(S, 0, (size_t)MM_ * MM_ * sizeof(float), stream);
        k1_mfma<<<dim3(4, 64), 512, 0, stream>>>(Jt_hi, Jt_lo, Ah, Al, Hc);
        k3_sim<<<dim3(8, 8, 8), 256, 0, stream>>>(msa_k, lw, S);
        k2_node<<<dim3(LL_), 512, 0, stream>>>(MSA, h, Hc, logp, out);
        k4_denom<<<dim3(MM_ / 64), 64, 0, stream>>>(S, lwsum, denom);
        k5_final<<<1, 512, 0, stream>>>(logp, lw, denom, dw, out);
    } else {
        float* ws = (float*)d_ws;
        float* msa_k = ws + OFF_MSAK;
        float* Hc    = ws + OFF_HC;
        float* logp  = ws + OFF_LOGP;
        float* S     = ws + OFF_S;
        float* denom = ws + OFF_DENOM;
        float* lwsum = ws + OFF_LWSUM;
        k0_transpose<<<dim3(LL_, MM_ / 256), 256, 0, stream>>>(MSA, msa_k);
        k_lwsum<<<1, 256, 0, stream>>>(lw, lwsum);
        hipMemsetAsync(S, 0, (size_t)MM_ * MM_ * sizeof(float), stream);
        k1_edge<<<dim3(MM_ / K1_BM, LL_ / K1_BL), 512, 0, stream>>>(J, msa_k, Hc);
        k3_sim<<<dim3(8, 8, 8), 256, 0, stream>>>(msa_k, lw, S);
        k2_node<<<dim3(LL_), 512, 0, stream>>>(MSA, h, Hc, logp, out);
        k4_denom<<<dim3(MM_ / 64), 64, 0, stream>>>(S, lwsum, denom);
        k5_final<<<1, 512, 0, stream>>>(logp, lw, denom, dw, out);
    }
}

// Round 10
// 851.619 us; speedup vs baseline: 1.4391x; 1.0042x over previous
//
#include <hip/hip_runtime.h>
#include <hip/hip_bf16.h>
#include <math.h>

// Problem constants (B=1)
#define LL_ 256   // L
#define MM_ 512   // M
#define AA_ 21    // A
#define CC_ 20    // A-1
#define KK_ (LL_*AA_)  // 5376
#define SIM_K 10.0f
#define SIM_MID 0.8f

typedef __attribute__((ext_vector_type(8))) short bf16x8;
typedef __attribute__((ext_vector_type(4))) float f32x4;
#define MFMA16 __builtin_amdgcn_mfma_f32_16x16x32_bf16

static __device__ __forceinline__ unsigned short f2bf(float x) {
    union { float f; unsigned u; } v; v.f = x;
    unsigned r = v.u + 0x7fffu + ((v.u >> 16) & 1u);
    return (unsigned short)(r >> 16);
}
static __device__ __forceinline__ float bf2f(unsigned short h) {
    union { unsigned u; float f; } v; v.u = ((unsigned)h) << 16; return v.f;
}

// ====================== NEW MFMA PATH =====================================
// ws byte offsets
#define B_JTHI  ((size_t)0)            // ushort[5376][5376]
#define B_JTLO  ((size_t)57802752)
#define B_AH    ((size_t)115605504)    // ushort[512][5376]
#define B_AL    ((size_t)121110528)
#define B_HC    ((size_t)126615552)    // float[512][5376]
#define B_MSAK  ((size_t)137625600)    // float[5376][512]
#define B_LOGP  ((size_t)148635648)    // float[256][512]
#define B_S     ((size_t)149159936)    // float[512][512]
#define B_DENOM ((size_t)150208512)    // float[512]
#define B_LWSUM ((size_t)150210560)    // float[1]
#define WS_NEED ((size_t)150210564)

// --- kT: J[l,p,c,a] (fp32) -> Jt_hi/lo[(l*21+c)][(p*21+a)] bf16 ------------
__global__ __launch_bounds__(256) void kT_jt(const float* __restrict__ J,
                                             unsigned short* __restrict__ Jt_hi,
                                             unsigned short* __restrict__ Jt_lo) {
    const int l = blockIdx.x;
    const int p0 = blockIdx.y * 32;
    const int tid = threadIdx.x;
    __shared__ float slab[32 * 441];  // 56.4 KB
    const float* Jb = J + ((size_t)l * 256 + p0) * 441;
    for (int i = tid; i < 32 * 441; i += 256) slab[i] = Jb[i];
    __syncthreads();
    // output granules: 21 rows (c) x 84 16B-granules (8 k each)
    for (int s = tid; s < 21 * 84; s += 256) {
        const int c = s / 84;
        const int kk8 = s - c * 84;
        bf16x8 hv, lv;
#pragma unroll
        for (int j = 0; j < 8; ++j) {
            const int kseg = kk8 * 8 + j;        // 0..671
            const int pl = kseg / 21;
            const int a = kseg - pl * 21;
            const float x = slab[pl * 441 + c * 21 + a];
            const unsigned short h = f2bf(x);
            hv[j] = (short)h;
            lv[j] = (short)f2bf(x - bf2f(h));
        }
        const size_t row = (size_t)(l * 21 + c);
        const size_t off = row * KK_ + p0 * 21 + kk8 * 8;
        *(bf16x8*)(Jt_hi + off) = hv;
        *(bf16x8*)(Jt_lo + off) = lv;
    }
}

// --- kA: MSA[p,m,a] -> Ah/Al[m][(p*21+a)] bf16 -----------------------------
__global__ __launch_bounds__(512) void kA_msa(const float* __restrict__ MSA,
                                              unsigned short* __restrict__ Ah,
                                              unsigned short* __restrict__ Al) {
    const int p0 = blockIdx.x * 8;
    const int m0 = blockIdx.y * 64;
    const int tid = threadIdx.x;
    __shared__ float slab[8 * 64 * 21];  // 43 KB : [pl][ml][a]
    for (int pl = 0; pl < 8; ++pl) {
        const float* src = MSA + ((size_t)(p0 + pl) * MM_ + m0) * AA_;
        for (int i = tid; i < 64 * 21; i += 512) slab[pl * 1344 + i] = src[i];
    }
    __syncthreads();
    const int ml = tid >> 3;
    const int pl = tid & 7;
    const size_t rowb = (size_t)(m0 + ml) * KK_ + (size_t)(p0 + pl) * 21;
#pragma unroll
    for (int a = 0; a < AA_; ++a) {
        const float x = slab[pl * 1344 + ml * 21 + a];
        const unsigned short h = f2bf(x);
        Ah[rowb + a] = h;
        Al[rowb + a] = f2bf(x - bf2f(h));
    }
}

// --- k1_mfma: Hc[m][n] = sum_k A[m][k] * Jt[n][k], 3-term bf16 split -------
// grid (4, 64): m0 = bx*128, lg = by (4 l's = 84 valid n). 512 threads.
// __launch_bounds__(512, 2): 2 waves/SIMD => 256-VGPR budget. The default
// budget (60 VGPR) spilled the prefetch registers -> ~1.2 GB scratch traffic
// per dispatch (WRITE_SIZE 947 MB, r7 profile). ~140 VGPR working set fits.
#define K1M_AROW 136   // ushort per LDS row: 64 hi + 64 lo + 8 pad
__global__ __launch_bounds__(512, 2) void k1_mfma(const unsigned short* __restrict__ Jt_hi,
                                                  const unsigned short* __restrict__ Jt_lo,
                                                  const unsigned short* __restrict__ Ah,
                                                  const unsigned short* __restrict__ Al,
                                                  float* __restrict__ Hc) {
    const int m0 = blockIdx.x * 128;
    const int lg = blockIdx.y;
    const int tid = threadIdx.x;
    const int lane = tid & 63;
    const int w = tid >> 6;
    const int wm = w >> 1;          // 0..3
    const int wn = w & 1;           // 0..1
    const int lr = lane & 15;
    const int lgk = lane >> 4;      // 0..3

    __shared__ unsigned short lds[(128 + 96) * K1M_AROW];  // 60.9 KB
    const int BOFF = 128 * K1M_AROW;

    // staging: 3584 granules of 16B = 7 per thread
    const unsigned short* sp[7];
    int dp[7];
#pragma unroll
    for (int i = 0; i < 7; ++i) {
        const int gid = tid + i * 512;
        if (gid < 2048) {  // A
            const int row = gid >> 4;
            const int g = gid & 15;
            const int pl = g >> 3;
            const int gg = g & 7;
            sp[i] = (pl ? Al : Ah) + (size_t)(m0 + row) * KK_ + gg * 8;
            dp[i] = row * K1M_AROW + pl * 64 + gg * 8;
        } else {           // B
            const int b = gid - 2048;
            const int row = b >> 4;
            const int g = b & 15;
            const int pl = g >> 3;
            const int gg = g & 7;
            int srow = lg * 84 + row; if (srow > 5375) srow = 5375;
            sp[i] = (pl ? Jt_lo : Jt_hi) + (size_t)srow * KK_ + gg * 8;
            dp[i] = BOFF + row * K1M_AROW + pl * 64 + gg * 8;
        }
    }

    f32x4 acc[2][3];
#pragma unroll
    for (int ms = 0; ms < 2; ++ms)
#pragma unroll
        for (int ns = 0; ns < 3; ++ns) acc[ms][ns] = (f32x4)(0.f);

    int4 r[7];
#pragma unroll
    for (int i = 0; i < 7; ++i) r[i] = *(const int4*)(sp[i]);

    for (int t = 0; t < 84; ++t) {
#pragma unroll
        for (int i = 0; i < 7; ++i) *(int4*)&lds[dp[i]] = r[i];
        __syncthreads();
        if (t < 83) {
            const size_t koff = (size_t)(t + 1) * 64;
#pragma unroll
            for (int i = 0; i < 7; ++i) r[i] = *(const int4*)(sp[i] + koff);
        }
#pragma unroll
        for (int kc = 0; kc < 2; ++kc) {
            bf16x8 a_h[2], a_l[2], b_h[3], b_l[3];
            const int kb = kc * 32 + lgk * 8;
#pragma unroll
            for (int ms = 0; ms < 2; ++ms) {
                const unsigned short* p = &lds[(wm * 32 + ms * 16 + lr) * K1M_AROW + kb];
                a_h[ms] = *(const bf16x8*)p;
                a_l[ms] = *(const bf16x8*)(p + 64);
            }
#pragma unroll
            for (int ns = 0; ns < 3; ++ns) {
                const unsigned short* p = &lds[BOFF + (wn * 48 + ns * 16 + lr) * K1M_AROW + kb];
                b_h[ns] = *(const bf16x8*)p;
                b_l[ns] = *(const bf16x8*)(p + 64);
            }
#pragma unroll
            for (int ms = 0; ms < 2; ++ms)
#pragma unroll
                for (int ns = 0; ns < 3; ++ns) {
                    acc[ms][ns] = MFMA16(a_h[ms], b_h[ns], acc[ms][ns], 0, 0, 0);
                    acc[ms][ns] = MFMA16(a_h[ms], b_l[ns], acc[ms][ns], 0, 0, 0);
                    acc[ms][ns] = MFMA16(a_l[ms], b_h[ns], acc[ms][ns], 0, 0, 0);
                }
        }
        __syncthreads();
    }
    // writeback: C row = (lane>>4)*4 + reg (m), col = lane&15 (n)  [m89]
#pragma unroll
    for (int ms = 0; ms < 2; ++ms)
#pragma unroll
        for (int ns = 0; ns < 3; ++ns) {
            const int nloc = wn * 48 + ns * 16 + lr;
            if (nloc < 84) {
                const size_t ng = (size_t)lg * 84 + nloc;
#pragma unroll
                for (int rr = 0; rr < 4; ++rr) {
                    const int m = m0 + wm * 32 + ms * 16 + lgk * 4 + rr;
                    Hc[(size_t)m * KK_ + ng] = acc[ms][ns][rr];
                }
            }
        }
}

// ====================== SHARED / OLD PATH KERNELS ==========================
// old-path ws offsets (floats)
#define OFF_MSAK   ((size_t)0)
#define OFF_HC     ((size_t)2752512)
#define OFF_LOGP   ((size_t)5505024)
#define OFF_S      ((size_t)5636096)
#define OFF_DENOM  ((size_t)5898240)
#define OFF_LWSUM  ((size_t)5898752)

__global__ __launch_bounds__(256) void k0_transpose(const float* __restrict__ MSA,
                                                    float* __restrict__ msa_k) {
    const int l = blockIdx.x;
    const int m = blockIdx.y * 256 + threadIdx.x;
    const float* src = MSA + ((size_t)l * MM_ + m) * AA_;
#pragma unroll
    for (int a = 0; a < AA_; ++a) msa_k[(size_t)(l * AA_ + a) * MM_ + m] = src[a];
}

__global__ __launch_bounds__(256) void k_lwsum(const float* __restrict__ lw,
                                               float* __restrict__ out) {
    const int t = threadIdx.x;
    float v = lw[t];
#pragma unroll
    for (int off = 32; off; off >>= 1) v += __shfl_down(v, off, 64);
    __shared__ float r[4];
    if ((t & 63) == 0) r[t >> 6] = v;
    __syncthreads();
    if (t == 0) out[0] = r[0] + r[1] + r[2] + r[3];
}

// old fp32 VALU edge GEMM (fallback only)
#define K1_BL 4
#define K1_BM 128
#define K1_PP 4
__global__ __launch_bounds__(512) void k1_edge(const float* __restrict__ Jg,
                                               const float* __restrict__ msa_k,
                                               float* __restrict__ Hc) {
    const int m0 = blockIdx.x * K1_BM;
    const int l0 = blockIdx.y * K1_BL;
    const int tid = threadIdx.x;
    const int mq = tid & 31;
    const int nq = tid >> 5;
    __shared__ float Jl[K1_PP][AA_][96];
    float acc[6][4];
#pragma unroll
    for (int j = 0; j < 6; ++j)
#pragma unroll
        for (int i = 0; i < 4; ++i) acc[j][i] = 0.f;
    const int nj = (nq < 4) ? 6 : 5;
    for (int p0 = 0; p0 < LL_; p0 += K1_PP) {
        __syncthreads();
        for (int idx = tid; idx < K1_BL * K1_PP * 441; idx += 512) {
            const int pair = idx / 441;
            const int f = idx - pair * 441;
            const int ll = pair >> 2;
            const int pp = pair & 3;
            const int c = f / 21;
            const int a = f - c * 21;
            Jl[pp][a][ll * 21 + c] =
                Jg[(size_t)(l0 + ll) * (LL_ * AA_ * AA_) + (size_t)(p0 + pp) * 441 + f];
        }
        __syncthreads();
#pragma unroll
        for (int pp = 0; pp < K1_PP; ++pp) {
#pragma unroll 7
            for (int a = 0; a < AA_; ++a) {
                const int k = (p0 + pp) * AA_ + a;
                const float4 av = *(const float4*)(msa_k + (size_t)k * MM_ + m0 + (mq << 2));
#pragma unroll
                for (int j = 0; j < 6; ++j) {
                    const float b = Jl[pp][a][nq + 16 * j];
                    acc[j][0] = fmaf(av.x, b, acc[j][0]);
                    acc[j][1] = fmaf(av.y, b, acc[j][1]);
                    acc[j][2] = fmaf(av.z, b, acc[j][2]);
                    acc[j][3] = fmaf(av.w, b, acc[j][3]);
                }
            }
        }
    }
    for (int j = 0; j < nj; ++j) {
        const int n = nq + 16 * j;
        const int ll = n / 21;
        const int c = n - ll * 21;
        const int l = l0 + ll;
#pragma unroll
        for (int i = 0; i < 4; ++i) {
            const int m = m0 + (mq << 2) + i;
            Hc[((size_t)m * LL_ + l) * AA_ + c] = acc[j][i];
        }
    }
}

__global__ __launch_bounds__(512) void k2_node(const float* __restrict__ MSA,
                                               const float* __restrict__ hvec,
                                               const float* __restrict__ Hc,
                                               float* __restrict__ logp,
                                               float* __restrict__ out) {
    const int l = blockIdx.x;
    const int m = threadIdx.x;
    __shared__ float hl[AA_];
    if (m < AA_) hl[m] = hvec[l * AA_ + m];
    __syncthreads();
    const float* msa = MSA + ((size_t)l * MM_ + m) * AA_;
    const float* hc = Hc + ((size_t)m * LL_ + l) * AA_;
    float msav[AA_], hcv[AA_];
#pragma unroll
    for (int a = 0; a < AA_; ++a) { msav[a] = msa[a]; hcv[a] = hc[a]; }
    float nodewt = 0.f, edgewt = 0.f;
#pragma unroll
    for (int a = 0; a < AA_; ++a) {
        nodewt = fmaf(msav[a], hl[a], nodewt);
        edgewt = fmaf(msav[a], hcv[a], edgewt);
    }
    float hd[CC_];
    float mx = -1e30f;
#pragma unroll
    for (int c = 0; c < CC_; ++c) {
        hd[c] = (hl[c] - nodewt) + (hcv[c] - edgewt);
        mx = fmaxf(mx, -hd[c]);
    }
    float s = 0.f;
#pragma unroll
    for (int c = 0; c < CC_; ++c) s += expf(-hd[c] - mx);
    const float lse = mx + logf(s);
    float lpsum = 0.f;
#pragma unroll
    for (int c = 0; c < CC_; ++c) lpsum = fmaf(-hd[c] - lse, msav[c], lpsum);
    logp[l * MM_ + m] = lpsum;
    if (m == 0) {
#pragma unroll
        for (int c = 0; c < CC_; ++c) out[l * CC_ + c] = hd[c];
    }
}

__global__ __launch_bounds__(256) void k3_sim(const float* __restrict__ msa_k,
                                              const float* __restrict__ lw,
                                              float* __restrict__ S) {
    const int m0 = blockIdx.x * 64;
    const int n0 = blockIdx.y * 64;
    const int l0 = blockIdx.z * 32;
    const int tid = threadIdx.x;
    const int tx = tid & 15;
    const int ty = tid >> 4;
    __shared__ __align__(16) float As[21][64];
    __shared__ __align__(16) float Bs[21][64];
    float acc[4][4];
#pragma unroll
    for (int i = 0; i < 4; ++i)
#pragma unroll
        for (int j = 0; j < 4; ++j) acc[i][j] = 0.f;
    for (int l = l0; l < l0 + 32; ++l) {
        __syncthreads();
        const float lwv = lw[l];
        for (int idx = tid; idx < 21 * 64; idx += 256) {
            const int kk = idx >> 6, mm = idx & 63;
            const size_t row = (size_t)(l * 21 + kk) * MM_;
            As[kk][mm] = msa_k[row + m0 + mm];
            Bs[kk][mm] = msa_k[row + n0 + mm] * lwv;
        }
        __syncthreads();
#pragma unroll 7
        for (int kk = 0; kk < 21; ++kk) {
            const float4 a4 = *(const float4*)&As[kk][tx * 4];
            const float4 b4 = *(const float4*)&Bs[kk][ty * 4];
            const float av[4] = {a4.x, a4.y, a4.z, a4.w};
            const float bv[4] = {b4.x, b4.y, b4.z, b4.w};
#pragma unroll
            for (int i = 0; i < 4; ++i)
#pragma unroll
                for (int j = 0; j < 4; ++j)
                    acc[i][j] = fmaf(av[i], bv[j], acc[i][j]);
        }
    }
#pragma unroll
    for (int i = 0; i < 4; ++i)
#pragma unroll
        for (int j = 0; j < 4; ++j)
            atomicAdd(&S[(size_t)(m0 + tx * 4 + i) * MM_ + n0 + ty * 4 + j], acc[i][j]);
}

__global__ __launch_bounds__(64) void k4_denom(const float* __restrict__ S,
                                               const float* __restrict__ lwsum_p,
                                               float* __restrict__ denom) {
    const int m = blockIdx.x * 64 + threadIdx.x;
    const float inv = 1.0f / lwsum_p[0];
    float s = 0.f;
    for (int n = 0; n < MM_; ++n) {
        const float sim = S[(size_t)n * MM_ + m] * inv;
        s += 1.0f / (1.0f + expf(-SIM_K * (sim - SIM_MID)));
    }
    denom[m] = s;
}

__global__ __launch_bounds__(512) void k5_final(const float* __restrict__ logp,
                                                const float* __restrict__ lw,
                                                const float* __restrict__ denom,
                                                const float* __restrict__ dw,
                                                float* __restrict__ out) {
    const int m = threadIdx.x;
    float lp = 0.f;
    for (int l = 0; l < LL_; ++l) lp = fmaf(logp[l * MM_ + m], lw[l], lp);
    const float sw = dw[m] / denom[m];
    float a = sw * lp, b = sw;
#pragma unroll
    for (int off = 32; off; off >>= 1) {
        a += __shfl_down(a, off, 64);
        b += __shfl_down(b, off, 64);
    }
    __shared__ float ra[8], rb[8];
    if ((m & 63) == 0) { ra[m >> 6] = a; rb[m >> 6] = b; }
    __syncthreads();
    if (m == 0) {
        float sa = 0.f, sb = 0.f;
#pragma unroll
        for (int w = 0; w < 8; ++w) { sa += ra[w]; sb += rb[w]; }
        out[5120] = sa / sb;
    }
}

extern "C" void kernel_launch(void* const* d_in, const int* in_sizes, int n_in,
                              void* d_out, int out_size, void* d_ws, size_t ws_size,
                              hipStream_t stream) {
    const float* MSA = (const float*)d_in[0];
    const float* h   = (const float*)d_in[1];
    const float* J   = (const float*)d_in[2];
    const float* lw  = (const float*)d_in[3];
    const float* dw  = (const float*)d_in[4];
    float* out = (float*)d_out;

    if (ws_size >= WS_NEED) {
        char* wsb = (char*)d_ws;
        unsigned short* Jt_hi = (unsigned short*)(wsb + B_JTHI);
        unsigned short* Jt_lo = (unsigned short*)(wsb + B_JTLO);
        unsigned short* Ah    = (unsigned short*)(wsb + B_AH);
        unsigned short* Al    = (unsigned short*)(wsb + B_AL);
        float* Hc    = (float*)(wsb + B_HC);
        float* msa_k = (float*)(wsb + B_MSAK);
        float* logp  = (float*)(wsb + B_LOGP);
        float* S     = (float*)(wsb + B_S);
        float* denom = (float*)(wsb + B_DENOM);
        float* lwsum = (float*)(wsb + B_LWSUM);

        kT_jt<<<dim3(LL_, 8), 256, 0, stream>>>(J, Jt_hi, Jt_lo);
        kA_msa<<<dim3(32, 8), 512, 0, stream>>>(MSA, Ah, Al);
        k0_transpose<<<dim3(LL_, MM_ / 256), 256, 0, stream>>>(MSA, msa_k);
        k_lwsum<<<1, 256, 0, stream>>>(lw, lwsum);
        hipMemsetAsync(S, 0, (size_t)MM_ * MM_ * sizeof(float), stream);
        k1_mfma<<<dim3(4, 64), 512, 0, stream>>>(Jt_hi, Jt_lo, Ah, Al, Hc);
        k3_sim<<<dim3(8, 8, 8), 256, 0, stream>>>(msa_k, lw, S);
        k2_node<<<dim3(LL_), 512, 0, stream>>>(MSA, h, Hc, logp, out);
        k4_denom<<<dim3(MM_ / 64), 64, 0, stream>>>(S, lwsum, denom);
        k5_final<<<1, 512, 0, stream>>>(logp, lw, denom, dw, out);
    } else {
        float* ws = (float*)d_ws;
        float* msa_k = ws + OFF_MSAK;
        float* Hc    = ws + OFF_HC;
        float* logp  = ws + OFF_LOGP;
        float* S     = ws + OFF_S;
        float* denom = ws + OFF_DENOM;
        float* lwsum = ws + OFF_LWSUM;
        k0_transpose<<<dim3(LL_, MM_ / 256), 256, 0, stream>>>(MSA, msa_k);
        k_lwsum<<<1, 256, 0, stream>>>(lw, lwsum);
        hipMemsetAsync(S, 0, (size_t)MM_ * MM_ * sizeof(float), stream);
        k1_edge<<<dim3(MM_ / K1_BM, LL_ / K1_BL), 512, 0, stream>>>(J, msa_k, Hc);
        k3_sim<<<dim3(8, 8, 8), 256, 0, stream>>>(msa_k, lw, S);
        k2_node<<<dim3(LL_), 512, 0, stream>>>(MSA, h, Hc, logp, out);
        k4_denom<<<dim3(MM_ / 64), 64, 0, stream>>>(S, lwsum, denom);
        k5_final<<<1, 512, 0, stream>>>(logp, lw, denom, dw, out);
    }
}

// Round 11
// 558.713 us; speedup vs baseline: 2.1936x; 1.5243x over previous
//
#include <hip/hip_runtime.h>
#include <hip/hip_bf16.h>
#include <math.h>

// Problem constants (B=1)
#define LL_ 256   // L
#define MM_ 512   // M
#define AA_ 21    // A
#define CC_ 20    // A-1
#define KK_ (LL_*AA_)  // 5376
#define SIM_K 10.0f
#define SIM_MID 0.8f

typedef __attribute__((ext_vector_type(8))) short bf16x8;
typedef __attribute__((ext_vector_type(4))) float f32x4;
#define MFMA16 __builtin_amdgcn_mfma_f32_16x16x32_bf16

static __device__ __forceinline__ unsigned short f2bf(float x) {
    union { float f; unsigned u; } v; v.f = x;
    unsigned r = v.u + 0x7fffu + ((v.u >> 16) & 1u);
    return (unsigned short)(r >> 16);
}
static __device__ __forceinline__ float bf2f(unsigned short h) {
    union { unsigned u; float f; } v; v.u = ((unsigned)h) << 16; return v.f;
}

// ====================== NEW MFMA PATH =====================================
// ws byte offsets
#define B_JTHI  ((size_t)0)            // ushort[5376][5376]
#define B_JTLO  ((size_t)57802752)
#define B_AH    ((size_t)115605504)    // ushort[512][5376]
#define B_AL    ((size_t)121110528)
#define B_HC    ((size_t)126615552)    // float[512][5376]
#define B_MSAK  ((size_t)137625600)    // float[5376][512]
#define B_LOGP  ((size_t)148635648)    // float[256][512]
#define B_S     ((size_t)149159936)    // float[512][512]
#define B_DENOM ((size_t)150208512)    // float[512]
#define B_LWSUM ((size_t)150210560)    // float[1]
#define WS_NEED ((size_t)150210564)

// --- kT: J[l,p,c,a] (fp32) -> Jt_hi/lo[(l*21+c)][(p*21+a)] bf16 ------------
__global__ __launch_bounds__(256) void kT_jt(const float* __restrict__ J,
                                             unsigned short* __restrict__ Jt_hi,
                                             unsigned short* __restrict__ Jt_lo) {
    const int l = blockIdx.x;
    const int p0 = blockIdx.y * 32;
    const int tid = threadIdx.x;
    __shared__ float slab[32 * 441];  // 56.4 KB
    const float* Jb = J + ((size_t)l * 256 + p0) * 441;
    for (int i = tid; i < 32 * 441; i += 256) slab[i] = Jb[i];
    __syncthreads();
    // output granules: 21 rows (c) x 84 16B-granules (8 k each)
    for (int s = tid; s < 21 * 84; s += 256) {
        const int c = s / 84;
        const int kk8 = s - c * 84;
        bf16x8 hv, lv;
#pragma unroll
        for (int j = 0; j < 8; ++j) {
            const int kseg = kk8 * 8 + j;        // 0..671
            const int pl = kseg / 21;
            const int a = kseg - pl * 21;
            const float x = slab[pl * 441 + c * 21 + a];
            const unsigned short h = f2bf(x);
            hv[j] = (short)h;
            lv[j] = (short)f2bf(x - bf2f(h));
        }
        const size_t row = (size_t)(l * 21 + c);
        const size_t off = row * KK_ + p0 * 21 + kk8 * 8;
        *(bf16x8*)(Jt_hi + off) = hv;
        *(bf16x8*)(Jt_lo + off) = lv;
    }
}

// --- kA: MSA[p,m,a] -> Ah/Al[m][(p*21+a)] bf16 -----------------------------
__global__ __launch_bounds__(512) void kA_msa(const float* __restrict__ MSA,
                                              unsigned short* __restrict__ Ah,
                                              unsigned short* __restrict__ Al) {
    const int p0 = blockIdx.x * 8;
    const int m0 = blockIdx.y * 64;
    const int tid = threadIdx.x;
    __shared__ float slab[8 * 64 * 21];  // 43 KB : [pl][ml][a]
    for (int pl = 0; pl < 8; ++pl) {
        const float* src = MSA + ((size_t)(p0 + pl) * MM_ + m0) * AA_;
        for (int i = tid; i < 64 * 21; i += 512) slab[pl * 1344 + i] = src[i];
    }
    __syncthreads();
    const int ml = tid >> 3;
    const int pl = tid & 7;
    const size_t rowb = (size_t)(m0 + ml) * KK_ + (size_t)(p0 + pl) * 21;
#pragma unroll
    for (int a = 0; a < AA_; ++a) {
        const float x = slab[pl * 1344 + ml * 21 + a];
        const unsigned short h = f2bf(x);
        Ah[rowb + a] = h;
        Al[rowb + a] = f2bf(x - bf2f(h));
    }
}

// --- k1_mfma: Hc[m][n] = sum_k A[m][k] * Jt[n][k], 3-term bf16 split -------
// grid (4, 64): m0 = bx*128, lg = by (4 l's = 84 valid n). 512 threads.
// r10 post-mortem: launch_bounds(512,2) alone left VGPR_Count=60 + 940 MB
// scratch writes. Two fixes:
//  (1) amdgpu_waves_per_eu(2,2): stop the allocator from targeting >2 waves/EU
//      (grid = 1 block/CU, so 2 waves/EU is the ceiling anyway).
//  (2) rule-#20: staging state was in arrays (sp[7]/dp[7]/r[7]) initialized
//      under a branch -> allocas in scratch. All named scalars now; slots 0-3
//      are statically A, 4-6 statically B (no branch).
#define K1M_AROW 136   // ushort per LDS row: 64 hi + 64 lo + 8 pad
__global__ __launch_bounds__(512, 2) __attribute__((amdgpu_waves_per_eu(2, 2)))
void k1_mfma(const unsigned short* __restrict__ Jt_hi,
             const unsigned short* __restrict__ Jt_lo,
             const unsigned short* __restrict__ Ah,
             const unsigned short* __restrict__ Al,
             float* __restrict__ Hc) {
    const int m0 = blockIdx.x * 128;
    const int lg = blockIdx.y;
    const int tid = threadIdx.x;
    const int lane = tid & 63;
    const int w = tid >> 6;
    const int wm = w >> 1;          // 0..3
    const int wn = w & 1;           // 0..1
    const int lr = lane & 15;
    const int lgk = lane >> 4;      // 0..3

    __shared__ unsigned short lds[(128 + 96) * K1M_AROW];  // 60.9 KB
    const int BOFF = 128 * K1M_AROW;

    // staging geometry: granule gid = tid + slot*512, 16B each.
    // slots 0-3 -> A rows 0..127; slots 4-6 -> B rows 0..95.
    const int pl = (tid >> 3) & 1;   // hi/lo plane
    const int gg = tid & 7;          // 16B granule within 64-k row half
    const int arow = tid >> 4;       // 0..31 (row step 32 per slot)
    const unsigned short* Abase = pl ? Al : Ah;
    const unsigned short* Bbase = pl ? Jt_lo : Jt_hi;

    const unsigned short* sp0 = Abase + (size_t)(m0 + arow +  0) * KK_ + gg * 8;
    const unsigned short* sp1 = Abase + (size_t)(m0 + arow + 32) * KK_ + gg * 8;
    const unsigned short* sp2 = Abase + (size_t)(m0 + arow + 64) * KK_ + gg * 8;
    const unsigned short* sp3 = Abase + (size_t)(m0 + arow + 96) * KK_ + gg * 8;
    int br0 = lg * 84 + arow;       if (br0 > 5375) br0 = 5375;
    int br1 = lg * 84 + arow + 32;  if (br1 > 5375) br1 = 5375;
    int br2 = lg * 84 + arow + 64;  if (br2 > 5375) br2 = 5375;
    const unsigned short* sp4 = Bbase + (size_t)br0 * KK_ + gg * 8;
    const unsigned short* sp5 = Bbase + (size_t)br1 * KK_ + gg * 8;
    const unsigned short* sp6 = Bbase + (size_t)br2 * KK_ + gg * 8;

    const int dbase = arow * K1M_AROW + pl * 64 + gg * 8;
    const int dp0 = dbase;
    const int dp1 = dbase + 32 * K1M_AROW;
    const int dp2 = dbase + 64 * K1M_AROW;
    const int dp3 = dbase + 96 * K1M_AROW;
    const int dp4 = BOFF + dbase;
    const int dp5 = BOFF + dbase + 32 * K1M_AROW;
    const int dp6 = BOFF + dbase + 64 * K1M_AROW;

    f32x4 acc00 = (f32x4)(0.f), acc01 = (f32x4)(0.f), acc02 = (f32x4)(0.f);
    f32x4 acc10 = (f32x4)(0.f), acc11 = (f32x4)(0.f), acc12 = (f32x4)(0.f);

    int4 r0 = *(const int4*)sp0;
    int4 r1 = *(const int4*)sp1;
    int4 r2 = *(const int4*)sp2;
    int4 r3 = *(const int4*)sp3;
    int4 r4 = *(const int4*)sp4;
    int4 r5 = *(const int4*)sp5;
    int4 r6 = *(const int4*)sp6;

    for (int t = 0; t < 84; ++t) {
        *(int4*)&lds[dp0] = r0;
        *(int4*)&lds[dp1] = r1;
        *(int4*)&lds[dp2] = r2;
        *(int4*)&lds[dp3] = r3;
        *(int4*)&lds[dp4] = r4;
        *(int4*)&lds[dp5] = r5;
        *(int4*)&lds[dp6] = r6;
        __syncthreads();
        if (t < 83) {
            const size_t koff = (size_t)(t + 1) * 64;
            r0 = *(const int4*)(sp0 + koff);
            r1 = *(const int4*)(sp1 + koff);
            r2 = *(const int4*)(sp2 + koff);
            r3 = *(const int4*)(sp3 + koff);
            r4 = *(const int4*)(sp4 + koff);
            r5 = *(const int4*)(sp5 + koff);
            r6 = *(const int4*)(sp6 + koff);
        }
#pragma unroll
        for (int kc = 0; kc < 2; ++kc) {
            const int kb = kc * 32 + lgk * 8;
            const unsigned short* pa0 = &lds[(wm * 32 + lr) * K1M_AROW + kb];
            const unsigned short* pa1 = &lds[(wm * 32 + 16 + lr) * K1M_AROW + kb];
            const unsigned short* pb0 = &lds[BOFF + (wn * 48 + lr) * K1M_AROW + kb];
            const unsigned short* pb1 = &lds[BOFF + (wn * 48 + 16 + lr) * K1M_AROW + kb];
            const unsigned short* pb2 = &lds[BOFF + (wn * 48 + 32 + lr) * K1M_AROW + kb];
            const bf16x8 ah0 = *(const bf16x8*)pa0;
            const bf16x8 al0 = *(const bf16x8*)(pa0 + 64);
            const bf16x8 ah1 = *(const bf16x8*)pa1;
            const bf16x8 al1 = *(const bf16x8*)(pa1 + 64);
            const bf16x8 bh0 = *(const bf16x8*)pb0;
            const bf16x8 bl0 = *(const bf16x8*)(pb0 + 64);
            const bf16x8 bh1 = *(const bf16x8*)pb1;
            const bf16x8 bl1 = *(const bf16x8*)(pb1 + 64);
            const bf16x8 bh2 = *(const bf16x8*)pb2;
            const bf16x8 bl2 = *(const bf16x8*)(pb2 + 64);
            acc00 = MFMA16(ah0, bh0, acc00, 0, 0, 0);
            acc00 = MFMA16(ah0, bl0, acc00, 0, 0, 0);
            acc00 = MFMA16(al0, bh0, acc00, 0, 0, 0);
            acc01 = MFMA16(ah0, bh1, acc01, 0, 0, 0);
            acc01 = MFMA16(ah0, bl1, acc01, 0, 0, 0);
            acc01 = MFMA16(al0, bh1, acc01, 0, 0, 0);
            acc02 = MFMA16(ah0, bh2, acc02, 0, 0, 0);
            acc02 = MFMA16(ah0, bl2, acc02, 0, 0, 0);
            acc02 = MFMA16(al0, bh2, acc02, 0, 0, 0);
            acc10 = MFMA16(ah1, bh0, acc10, 0, 0, 0);
            acc10 = MFMA16(ah1, bl0, acc10, 0, 0, 0);
            acc10 = MFMA16(al1, bh0, acc10, 0, 0, 0);
            acc11 = MFMA16(ah1, bh1, acc11, 0, 0, 0);
            acc11 = MFMA16(ah1, bl1, acc11, 0, 0, 0);
            acc11 = MFMA16(al1, bh1, acc11, 0, 0, 0);
            acc12 = MFMA16(ah1, bh2, acc12, 0, 0, 0);
            acc12 = MFMA16(ah1, bl2, acc12, 0, 0, 0);
            acc12 = MFMA16(al1, bh2, acc12, 0, 0, 0);
        }
        __syncthreads();
    }
    // writeback: C row(m) = (lane>>4)*4 + reg, col(n) = lane&15  [m89]
#define K1M_WRITE(ACC, MS, NS)                                                  \
    do {                                                                        \
        const int nloc = wn * 48 + (NS) * 16 + lr;                              \
        if (nloc < 84) {                                                        \
            const size_t ng = (size_t)lg * 84 + nloc;                           \
            const int mb = m0 + wm * 32 + (MS) * 16 + lgk * 4;                  \
            Hc[(size_t)(mb + 0) * KK_ + ng] = (ACC)[0];                         \
            Hc[(size_t)(mb + 1) * KK_ + ng] = (ACC)[1];                         \
            Hc[(size_t)(mb + 2) * KK_ + ng] = (ACC)[2];                         \
            Hc[(size_t)(mb + 3) * KK_ + ng] = (ACC)[3];                         \
        }                                                                       \
    } while (0)
    K1M_WRITE(acc00, 0, 0);
    K1M_WRITE(acc01, 0, 1);
    K1M_WRITE(acc02, 0, 2);
    K1M_WRITE(acc10, 1, 0);
    K1M_WRITE(acc11, 1, 1);
    K1M_WRITE(acc12, 1, 2);
#undef K1M_WRITE
}

// ====================== SHARED / OLD PATH KERNELS ==========================
// old-path ws offsets (floats)
#define OFF_MSAK   ((size_t)0)
#define OFF_HC     ((size_t)2752512)
#define OFF_LOGP   ((size_t)5505024)
#define OFF_S      ((size_t)5636096)
#define OFF_DENOM  ((size_t)5898240)
#define OFF_LWSUM  ((size_t)5898752)

__global__ __launch_bounds__(256) void k0_transpose(const float* __restrict__ MSA,
                                                    float* __restrict__ msa_k) {
    const int l = blockIdx.x;
    const int m = blockIdx.y * 256 + threadIdx.x;
    const float* src = MSA + ((size_t)l * MM_ + m) * AA_;
#pragma unroll
    for (int a = 0; a < AA_; ++a) msa_k[(size_t)(l * AA_ + a) * MM_ + m] = src[a];
}

__global__ __launch_bounds__(256) void k_lwsum(const float* __restrict__ lw,
                                               float* __restrict__ out) {
    const int t = threadIdx.x;
    float v = lw[t];
#pragma unroll
    for (int off = 32; off; off >>= 1) v += __shfl_down(v, off, 64);
    __shared__ float r[4];
    if ((t & 63) == 0) r[t >> 6] = v;
    __syncthreads();
    if (t == 0) out[0] = r[0] + r[1] + r[2] + r[3];
}

// old fp32 VALU edge GEMM (fallback only)
#define K1_BL 4
#define K1_BM 128
#define K1_PP 4
__global__ __launch_bounds__(512) void k1_edge(const float* __restrict__ Jg,
                                               const float* __restrict__ msa_k,
                                               float* __restrict__ Hc) {
    const int m0 = blockIdx.x * K1_BM;
    const int l0 = blockIdx.y * K1_BL;
    const int tid = threadIdx.x;
    const int mq = tid & 31;
    const int nq = tid >> 5;
    __shared__ float Jl[K1_PP][AA_][96];
    float acc[6][4];
#pragma unroll
    for (int j = 0; j < 6; ++j)
#pragma unroll
        for (int i = 0; i < 4; ++i) acc[j][i] = 0.f;
    const int nj = (nq < 4) ? 6 : 5;
    for (int p0 = 0; p0 < LL_; p0 += K1_PP) {
        __syncthreads();
        for (int idx = tid; idx < K1_BL * K1_PP * 441; idx += 512) {
            const int pair = idx / 441;
            const int f = idx - pair * 441;
            const int ll = pair >> 2;
            const int pp = pair & 3;
            const int c = f / 21;
            const int a = f - c * 21;
            Jl[pp][a][ll * 21 + c] =
                Jg[(size_t)(l0 + ll) * (LL_ * AA_ * AA_) + (size_t)(p0 + pp) * 441 + f];
        }
        __syncthreads();
#pragma unroll
        for (int pp = 0; pp < K1_PP; ++pp) {
#pragma unroll 7
            for (int a = 0; a < AA_; ++a) {
                const int k = (p0 + pp) * AA_ + a;
                const float4 av = *(const float4*)(msa_k + (size_t)k * MM_ + m0 + (mq << 2));
#pragma unroll
                for (int j = 0; j < 6; ++j) {
                    const float b = Jl[pp][a][nq + 16 * j];
                    acc[j][0] = fmaf(av.x, b, acc[j][0]);
                    acc[j][1] = fmaf(av.y, b, acc[j][1]);
                    acc[j][2] = fmaf(av.z, b, acc[j][2]);
                    acc[j][3] = fmaf(av.w, b, acc[j][3]);
                }
            }
        }
    }
    for (int j = 0; j < nj; ++j) {
        const int n = nq + 16 * j;
        const int ll = n / 21;
        const int c = n - ll * 21;
        const int l = l0 + ll;
#pragma unroll
        for (int i = 0; i < 4; ++i) {
            const int m = m0 + (mq << 2) + i;
            Hc[((size_t)m * LL_ + l) * AA_ + c] = acc[j][i];
        }
    }
}

__global__ __launch_bounds__(512) void k2_node(const float* __restrict__ MSA,
                                               const float* __restrict__ hvec,
                                               const float* __restrict__ Hc,
                                               float* __restrict__ logp,
                                               float* __restrict__ out) {
    const int l = blockIdx.x;
    const int m = threadIdx.x;
    __shared__ float hl[AA_];
    if (m < AA_) hl[m] = hvec[l * AA_ + m];
    __syncthreads();
    const float* msa = MSA + ((size_t)l * MM_ + m) * AA_;
    const float* hc = Hc + ((size_t)m * LL_ + l) * AA_;
    float msav[AA_], hcv[AA_];
#pragma unroll
    for (int a = 0; a < AA_; ++a) { msav[a] = msa[a]; hcv[a] = hc[a]; }
    float nodewt = 0.f, edgewt = 0.f;
#pragma unroll
    for (int a = 0; a < AA_; ++a) {
        nodewt = fmaf(msav[a], hl[a], nodewt);
        edgewt = fmaf(msav[a], hcv[a], edgewt);
    }
    float hd[CC_];
    float mx = -1e30f;
#pragma unroll
    for (int c = 0; c < CC_; ++c) {
        hd[c] = (hl[c] - nodewt) + (hcv[c] - edgewt);
        mx = fmaxf(mx, -hd[c]);
    }
    float s = 0.f;
#pragma unroll
    for (int c = 0; c < CC_; ++c) s += expf(-hd[c] - mx);
    const float lse = mx + logf(s);
    float lpsum = 0.f;
#pragma unroll
    for (int c = 0; c < CC_; ++c) lpsum = fmaf(-hd[c] - lse, msav[c], lpsum);
    logp[l * MM_ + m] = lpsum;
    if (m == 0) {
#pragma unroll
        for (int c = 0; c < CC_; ++c) out[l * CC_ + c] = hd[c];
    }
}

__global__ __launch_bounds__(256) void k3_sim(const float* __restrict__ msa_k,
                                              const float* __restrict__ lw,
                                              float* __restrict__ S) {
    const int m0 = blockIdx.x * 64;
    const int n0 = blockIdx.y * 64;
    const int l0 = blockIdx.z * 32;
    const int tid = threadIdx.x;
    const int tx = tid & 15;
    const int ty = tid >> 4;
    __shared__ __align__(16) float As[21][64];
    __shared__ __align__(16) float Bs[21][64];
    float acc[4][4];
#pragma unroll
    for (int i = 0; i < 4; ++i)
#pragma unroll
        for (int j = 0; j < 4; ++j) acc[i][j] = 0.f;
    for (int l = l0; l < l0 + 32; ++l) {
        __syncthreads();
        const float lwv = lw[l];
        for (int idx = tid; idx < 21 * 64; idx += 256) {
            const int kk = idx >> 6, mm = idx & 63;
            const size_t row = (size_t)(l * 21 + kk) * MM_;
            As[kk][mm] = msa_k[row + m0 + mm];
            Bs[kk][mm] = msa_k[row + n0 + mm] * lwv;
        }
        __syncthreads();
#pragma unroll 7
        for (int kk = 0; kk < 21; ++kk) {
            const float4 a4 = *(const float4*)&As[kk][tx * 4];
            const float4 b4 = *(const float4*)&Bs[kk][ty * 4];
            const float av[4] = {a4.x, a4.y, a4.z, a4.w};
            const float bv[4] = {b4.x, b4.y, b4.z, b4.w};
#pragma unroll
            for (int i = 0; i < 4; ++i)
#pragma unroll
                for (int j = 0; j < 4; ++j)
                    acc[i][j] = fmaf(av[i], bv[j], acc[i][j]);
        }
    }
#pragma unroll
    for (int i = 0; i < 4; ++i)
#pragma unroll
        for (int j = 0; j < 4; ++j)
            atomicAdd(&S[(size_t)(m0 + tx * 4 + i) * MM_ + n0 + ty * 4 + j], acc[i][j]);
}

__global__ __launch_bounds__(64) void k4_denom(const float* __restrict__ S,
                                               const float* __restrict__ lwsum_p,
                                               float* __restrict__ denom) {
    const int m = blockIdx.x * 64 + threadIdx.x;
    const float inv = 1.0f / lwsum_p[0];
    float s = 0.f;
    for (int n = 0; n < MM_; ++n) {
        const float sim = S[(size_t)n * MM_ + m] * inv;
        s += 1.0f / (1.0f + expf(-SIM_K * (sim - SIM_MID)));
    }
    denom[m] = s;
}

__global__ __launch_bounds__(512) void k5_final(const float* __restrict__ logp,
                                                const float* __restrict__ lw,
                                                const float* __restrict__ denom,
                                                const float* __restrict__ dw,
                                                float* __restrict__ out) {
    const int m = threadIdx.x;
    float lp = 0.f;
    for (int l = 0; l < LL_; ++l) lp = fmaf(logp[l * MM_ + m], lw[l], lp);
    const float sw = dw[m] / denom[m];
    float a = sw * lp, b = sw;
#pragma unroll
    for (int off = 32; off; off >>= 1) {
        a += __shfl_down(a, off, 64);
        b += __shfl_down(b, off, 64);
    }
    __shared__ float ra[8], rb[8];
    if ((m & 63) == 0) { ra[m >> 6] = a; rb[m >> 6] = b; }
    __syncthreads();
    if (m == 0) {
        float sa = 0.f, sb = 0.f;
#pragma unroll
        for (int w = 0; w < 8; ++w) { sa += ra[w]; sb += rb[w]; }
        out[5120] = sa / sb;
    }
}

extern "C" void kernel_launch(void* const* d_in, const int* in_sizes, int n_in,
                              void* d_out, int out_size, void* d_ws, size_t ws_size,
                              hipStream_t stream) {
    const float* MSA = (const float*)d_in[0];
    const float* h   = (const float*)d_in[1];
    const float* J   = (const float*)d_in[2];
    const float* lw  = (const float*)d_in[3];
    const float* dw  = (const float*)d_in[4];
    float* out = (float*)d_out;

    if (ws_size >= WS_NEED) {
        char* wsb = (char*)d_ws;
        unsigned short* Jt_hi = (unsigned short*)(wsb + B_JTHI);
        unsigned short* Jt_lo = (unsigned short*)(wsb + B_JTLO);
        unsigned short* Ah    = (unsigned short*)(wsb + B_AH);
        unsigned short* Al    = (unsigned short*)(wsb + B_AL);
        float* Hc    = (float*)(wsb + B_HC);
        float* msa_k = (float*)(wsb + B_MSAK);
        float* logp  = (float*)(wsb + B_LOGP);
        float* S     = (float*)(wsb + B_S);
        float* denom = (float*)(wsb + B_DENOM);
        float* lwsum = (float*)(wsb + B_LWSUM);

        kT_jt<<<dim3(LL_, 8), 256, 0, stream>>>(J, Jt_hi, Jt_lo);
        kA_msa<<<dim3(32, 8), 512, 0, stream>>>(MSA, Ah, Al);
        k0_transpose<<<dim3(LL_, MM_ / 256), 256, 0, stream>>>(MSA, msa_k);
        k_lwsum<<<1, 256, 0, stream>>>(lw, lwsum);
        hipMemsetAsync(S, 0, (size_t)MM_ * MM_ * sizeof(float), stream);
        k1_mfma<<<dim3(4, 64), 512, 0, stream>>>(Jt_hi, Jt_lo, Ah, Al, Hc);
        k3_sim<<<dim3(8, 8, 8), 256, 0, stream>>>(msa_k, lw, S);
        k2_node<<<dim3(LL_), 512, 0, stream>>>(MSA, h, Hc, logp, out);
        k4_denom<<<dim3(MM_ / 64), 64, 0, stream>>>(S, lwsum, denom);
        k5_final<<<1, 512, 0, stream>>>(logp, lw, denom, dw, out);
    } else {
        float* ws = (float*)d_ws;
        float* msa_k = ws + OFF_MSAK;
        float* Hc    = ws + OFF_HC;
        float* logp  = ws + OFF_LOGP;
        float* S     = ws + OFF_S;
        float* denom = ws + OFF_DENOM;
        float* lwsum = ws + OFF_LWSUM;
        k0_transpose<<<dim3(LL_, MM_ / 256), 256, 0, stream>>>(MSA, msa_k);
        k_lwsum<<<1, 256, 0, stream>>>(lw, lwsum);
        hipMemsetAsync(S, 0, (size_t)MM_ * MM_ * sizeof(float), stream);
        k1_edge<<<dim3(MM_ / K1_BM, LL_ / K1_BL), 512, 0, stream>>>(J, msa_k, Hc);
        k3_sim<<<dim3(8, 8, 8), 256, 0, stream>>>(msa_k, lw, S);
        k2_node<<<dim3(LL_), 512, 0, stream>>>(MSA, h, Hc, logp, out);
        k4_denom<<<dim3(MM_ / 64), 64, 0, stream>>>(S, lwsum, denom);
        k5_final<<<1, 512, 0, stream>>>(logp, lw, denom, dw, out);
    }
}

// Round 14
// 547.207 us; speedup vs baseline: 2.2397x; 1.0210x over previous
//
#include <hip/hip_runtime.h>
#include <hip/hip_bf16.h>
#include <math.h>

// Problem constants (B=1)
#define LL_ 256   // L
#define MM_ 512   // M
#define AA_ 21    // A
#define CC_ 20    // A-1
#define KK_ (LL_*AA_)  // 5376
#define SIM_K 10.0f
#define SIM_MID 0.8f

typedef __attribute__((ext_vector_type(8))) short bf16x8;
typedef __attribute__((ext_vector_type(4))) float f32x4;
#define MFMA16 __builtin_amdgcn_mfma_f32_16x16x32_bf16

static __device__ __forceinline__ unsigned short f2bf(float x) {
    union { float f; unsigned u; } v; v.f = x;
    unsigned r = v.u + 0x7fffu + ((v.u >> 16) & 1u);
    return (unsigned short)(r >> 16);
}
static __device__ __forceinline__ float bf2f(unsigned short h) {
    union { unsigned u; float f; } v; v.u = ((unsigned)h) << 16; return v.f;
}

// ====================== NEW MFMA PATH =====================================
// ws byte offsets
#define B_JTHI  ((size_t)0)            // ushort[5376][5376]
#define B_JTLO  ((size_t)57802752)
#define B_AH    ((size_t)115605504)    // ushort[512][5376]
#define B_AL    ((size_t)121110528)
#define B_HC    ((size_t)126615552)    // float[512][5376]
#define B_MSAK  ((size_t)137625600)    // float[5376][512]
#define B_LOGP  ((size_t)148635648)    // float[256][512]
#define B_S     ((size_t)149159936)    // float[512][512]
#define B_DENOM ((size_t)150208512)    // float[512]
#define B_LWSUM ((size_t)150210560)    // float[1]
#define WS_NEED ((size_t)150210564)

// --- kT: J[l,p,c,a] (fp32) -> Jt_hi/lo[(l*21+c)][(p*21+a)] bf16 ------------
// r11: slab load was 55 scalar dword loads/thread (G13). Base is 16B-aligned:
// (l*256+p0)*441*4 = l*451584 + by*56448, both /16. float4 -> 14 iters.
__global__ __launch_bounds__(256) void kT_jt(const float* __restrict__ J,
                                             unsigned short* __restrict__ Jt_hi,
                                             unsigned short* __restrict__ Jt_lo) {
    const int l = blockIdx.x;
    const int p0 = blockIdx.y * 32;
    const int tid = threadIdx.x;
    __shared__ float slab[32 * 441];  // 56.4 KB
    const float4* Jb4 = (const float4*)(J + ((size_t)l * 256 + p0) * 441);
    float4* slab4 = (float4*)slab;
    for (int i = tid; i < (32 * 441) / 4; i += 256) slab4[i] = Jb4[i];
    __syncthreads();
    // output granules: 21 rows (c) x 84 16B-granules (8 k each)
    for (int s = tid; s < 21 * 84; s += 256) {
        const int c = s / 84;
        const int kk8 = s - c * 84;
        bf16x8 hv, lv;
#pragma unroll
        for (int j = 0; j < 8; ++j) {
            const int kseg = kk8 * 8 + j;        // 0..671
            const int pl = kseg / 21;
            const int a = kseg - pl * 21;
            const float x = slab[pl * 441 + c * 21 + a];
            const unsigned short h = f2bf(x);
            hv[j] = (short)h;
            lv[j] = (short)f2bf(x - bf2f(h));
        }
        const size_t row = (size_t)(l * 21 + c);
        const size_t off = row * KK_ + p0 * 21 + kk8 * 8;
        *(bf16x8*)(Jt_hi + off) = hv;
        *(bf16x8*)(Jt_lo + off) = lv;
    }
}

// --- kA: MSA[p,m,a] -> Ah/Al[m][(p*21+a)] bf16 -----------------------------
__global__ __launch_bounds__(512) void kA_msa(const float* __restrict__ MSA,
                                              unsigned short* __restrict__ Ah,
                                              unsigned short* __restrict__ Al) {
    const int p0 = blockIdx.x * 8;
    const int m0 = blockIdx.y * 64;
    const int tid = threadIdx.x;
    __shared__ float slab[8 * 64 * 21];  // 43 KB : [pl][ml][a]
    for (int pl = 0; pl < 8; ++pl) {
        const float* src = MSA + ((size_t)(p0 + pl) * MM_ + m0) * AA_;
        for (int i = tid; i < 64 * 21; i += 512) slab[pl * 1344 + i] = src[i];
    }
    __syncthreads();
    const int ml = tid >> 3;
    const int pl = tid & 7;
    const size_t rowb = (size_t)(m0 + ml) * KK_ + (size_t)(p0 + pl) * 21;
#pragma unroll
    for (int a = 0; a < AA_; ++a) {
        const float x = slab[pl * 1344 + ml * 21 + a];
        const unsigned short h = f2bf(x);
        Ah[rowb + a] = h;
        Al[rowb + a] = f2bf(x - bf2f(h));
    }
}

// --- k1_mfma: Hc[m][n] += sum_k A[m][k] * Jt[n][k], 3-term bf16 split ------
// r11 landed 139 us but Occupancy=21%: grid 256 = 1 block/CU caps at
// 2 waves/SIMD, latency-bound (VALUBusy 9%). K-SPLIT 2: grid (4,64,2),
// each block does 42 k-steps, atomicAdd into zeroed Hc. LDS bytes/CU and
// HBM traffic unchanged; 2 blocks/CU -> 4 waves/SIMD. VGPR=64 fits the
// 128 cap from launch_bounds(512,4)+waves_per_eu(4).
#define K1M_AROW 136   // ushort per LDS row: 64 hi + 64 lo + 8 pad
__global__ __launch_bounds__(512, 4) __attribute__((amdgpu_waves_per_eu(4)))
void k1_mfma(const unsigned short* __restrict__ Jt_hi,
             const unsigned short* __restrict__ Jt_lo,
             const unsigned short* __restrict__ Ah,
             const unsigned short* __restrict__ Al,
             float* __restrict__ Hc) {
    const int m0 = blockIdx.x * 128;
    const int lg = blockIdx.y;
    const int ks = blockIdx.z;      // K-split half: k-steps [ks*42, ks*42+42)
    const int tid = threadIdx.x;
    const int lane = tid & 63;
    const int w = tid >> 6;
    const int wm = w >> 1;          // 0..3
    const int wn = w & 1;           // 0..1
    const int lr = lane & 15;
    const int lgk = lane >> 4;      // 0..3

    __shared__ unsigned short lds[(128 + 96) * K1M_AROW];  // 60.9 KB
    const int BOFF = 128 * K1M_AROW;

    // staging geometry: granule gid = tid + slot*512, 16B each.
    // slots 0-3 -> A rows 0..127; slots 4-6 -> B rows 0..95.
    const int pl = (tid >> 3) & 1;   // hi/lo plane
    const int gg = tid & 7;          // 16B granule within 64-k row half
    const int arow = tid >> 4;       // 0..31 (row step 32 per slot)
    const unsigned short* Abase = pl ? Al : Ah;
    const unsigned short* Bbase = pl ? Jt_lo : Jt_hi;
    const size_t k0 = (size_t)ks * 42 * 64;   // K offset of this split half

    const unsigned short* sp0 = Abase + (size_t)(m0 + arow +  0) * KK_ + k0 + gg * 8;
    const unsigned short* sp1 = Abase + (size_t)(m0 + arow + 32) * KK_ + k0 + gg * 8;
    const unsigned short* sp2 = Abase + (size_t)(m0 + arow + 64) * KK_ + k0 + gg * 8;
    const unsigned short* sp3 = Abase + (size_t)(m0 + arow + 96) * KK_ + k0 + gg * 8;
    int br0 = lg * 84 + arow;       if (br0 > 5375) br0 = 5375;
    int br1 = lg * 84 + arow + 32;  if (br1 > 5375) br1 = 5375;
    int br2 = lg * 84 + arow + 64;  if (br2 > 5375) br2 = 5375;
    const unsigned short* sp4 = Bbase + (size_t)br0 * KK_ + k0 + gg * 8;
    const unsigned short* sp5 = Bbase + (size_t)br1 * KK_ + k0 + gg * 8;
    const unsigned short* sp6 = Bbase + (size_t)br2 * KK_ + k0 + gg * 8;

    const int dbase = arow * K1M_AROW + pl * 64 + gg * 8;
    const int dp0 = dbase;
    const int dp1 = dbase + 32 * K1M_AROW;
    const int dp2 = dbase + 64 * K1M_AROW;
    const int dp3 = dbase + 96 * K1M_AROW;
    const int dp4 = BOFF + dbase;
    const int dp5 = BOFF + dbase + 32 * K1M_AROW;
    const int dp6 = BOFF + dbase + 64 * K1M_AROW;

    f32x4 acc00 = (f32x4)(0.f), acc01 = (f32x4)(0.f), acc02 = (f32x4)(0.f);
    f32x4 acc10 = (f32x4)(0.f), acc11 = (f32x4)(0.f), acc12 = (f32x4)(0.f);

    int4 r0 = *(const int4*)sp0;
    int4 r1 = *(const int4*)sp1;
    int4 r2 = *(const int4*)sp2;
    int4 r3 = *(const int4*)sp3;
    int4 r4 = *(const int4*)sp4;
    int4 r5 = *(const int4*)sp5;
    int4 r6 = *(const int4*)sp6;

    for (int t = 0; t < 42; ++t) {
        *(int4*)&lds[dp0] = r0;
        *(int4*)&lds[dp1] = r1;
        *(int4*)&lds[dp2] = r2;
        *(int4*)&lds[dp3] = r3;
        *(int4*)&lds[dp4] = r4;
        *(int4*)&lds[dp5] = r5;
        *(int4*)&lds[dp6] = r6;
        __syncthreads();
        if (t < 41) {
            const size_t koff = (size_t)(t + 1) * 64;
            r0 = *(const int4*)(sp0 + koff);
            r1 = *(const int4*)(sp1 + koff);
            r2 = *(const int4*)(sp2 + koff);
            r3 = *(const int4*)(sp3 + koff);
            r4 = *(const int4*)(sp4 + koff);
            r5 = *(const int4*)(sp5 + koff);
            r6 = *(const int4*)(sp6 + koff);
        }
#pragma unroll
        for (int kc = 0; kc < 2; ++kc) {
            const int kb = kc * 32 + lgk * 8;
            const unsigned short* pa0 = &lds[(wm * 32 + lr) * K1M_AROW + kb];
            const unsigned short* pa1 = &lds[(wm * 32 + 16 + lr) * K1M_AROW + kb];
            const unsigned short* pb0 = &lds[BOFF + (wn * 48 + lr) * K1M_AROW + kb];
            const unsigned short* pb1 = &lds[BOFF + (wn * 48 + 16 + lr) * K1M_AROW + kb];
            const unsigned short* pb2 = &lds[BOFF + (wn * 48 + 32 + lr) * K1M_AROW + kb];
            const bf16x8 ah0 = *(const bf16x8*)pa0;
            const bf16x8 al0 = *(const bf16x8*)(pa0 + 64);
            const bf16x8 ah1 = *(const bf16x8*)pa1;
            const bf16x8 al1 = *(const bf16x8*)(pa1 + 64);
            const bf16x8 bh0 = *(const bf16x8*)pb0;
            const bf16x8 bl0 = *(const bf16x8*)(pb0 + 64);
            const bf16x8 bh1 = *(const bf16x8*)pb1;
            const bf16x8 bl1 = *(const bf16x8*)(pb1 + 64);
            const bf16x8 bh2 = *(const bf16x8*)pb2;
            const bf16x8 bl2 = *(const bf16x8*)(pb2 + 64);
            acc00 = MFMA16(ah0, bh0, acc00, 0, 0, 0);
            acc00 = MFMA16(ah0, bl0, acc00, 0, 0, 0);
            acc00 = MFMA16(al0, bh0, acc00, 0, 0, 0);
            acc01 = MFMA16(ah0, bh1, acc01, 0, 0, 0);
            acc01 = MFMA16(ah0, bl1, acc01, 0, 0, 0);
            acc01 = MFMA16(al0, bh1, acc01, 0, 0, 0);
            acc02 = MFMA16(ah0, bh2, acc02, 0, 0, 0);
            acc02 = MFMA16(ah0, bl2, acc02, 0, 0, 0);
            acc02 = MFMA16(al0, bh2, acc02, 0, 0, 0);
            acc10 = MFMA16(ah1, bh0, acc10, 0, 0, 0);
            acc10 = MFMA16(ah1, bl0, acc10, 0, 0, 0);
            acc10 = MFMA16(al1, bh0, acc10, 0, 0, 0);
            acc11 = MFMA16(ah1, bh1, acc11, 0, 0, 0);
            acc11 = MFMA16(ah1, bl1, acc11, 0, 0, 0);
            acc11 = MFMA16(al1, bh1, acc11, 0, 0, 0);
            acc12 = MFMA16(ah1, bh2, acc12, 0, 0, 0);
            acc12 = MFMA16(ah1, bl2, acc12, 0, 0, 0);
            acc12 = MFMA16(al1, bh2, acc12, 0, 0, 0);
        }
        __syncthreads();
    }
    // writeback: C row(m) = (lane>>4)*4 + reg, col(n) = lane&15  [m89]
    // K-split partials combine via fp32 atomicAdd into zeroed Hc.
#define K1M_WRITE(ACC, MS, NS)                                                  \
    do {                                                                        \
        const int nloc = wn * 48 + (NS) * 16 + lr;                              \
        if (nloc < 84) {                                                        \
            const size_t ng = (size_t)lg * 84 + nloc;                           \
            const int mb = m0 + wm * 32 + (MS) * 16 + lgk * 4;                  \
            atomicAdd(&Hc[(size_t)(mb + 0) * KK_ + ng], (ACC)[0]);              \
            atomicAdd(&Hc[(size_t)(mb + 1) * KK_ + ng], (ACC)[1]);              \
            atomicAdd(&Hc[(size_t)(mb + 2) * KK_ + ng], (ACC)[2]);              \
            atomicAdd(&Hc[(size_t)(mb + 3) * KK_ + ng], (ACC)[3]);              \
        }                                                                       \
    } while (0)
    K1M_WRITE(acc00, 0, 0);
    K1M_WRITE(acc01, 0, 1);
    K1M_WRITE(acc02, 0, 2);
    K1M_WRITE(acc10, 1, 0);
    K1M_WRITE(acc11, 1, 1);
    K1M_WRITE(acc12, 1, 2);
#undef K1M_WRITE
}

// ====================== SHARED / OLD PATH KERNELS ==========================
// old-path ws offsets (floats)
#define OFF_MSAK   ((size_t)0)
#define OFF_HC     ((size_t)2752512)
#define OFF_LOGP   ((size_t)5505024)
#define OFF_S      ((size_t)5636096)
#define OFF_DENOM  ((size_t)5898240)
#define OFF_LWSUM  ((size_t)5898752)

__global__ __launch_bounds__(256) void k0_transpose(const float* __restrict__ MSA,
                                                    float* __restrict__ msa_k) {
    const int l = blockIdx.x;
    const int m = blockIdx.y * 256 + threadIdx.x;
    const float* src = MSA + ((size_t)l * MM_ + m) * AA_;
#pragma unroll
    for (int a = 0; a < AA_; ++a) msa_k[(size_t)(l * AA_ + a) * MM_ + m] = src[a];
}

__global__ __launch_bounds__(256) void k_lwsum(const float* __restrict__ lw,
                                               float* __restrict__ out) {
    const int t = threadIdx.x;
    float v = lw[t];
#pragma unroll
    for (int off = 32; off; off >>= 1) v += __shfl_down(v, off, 64);
    __shared__ float r[4];
    if ((t & 63) == 0) r[t >> 6] = v;
    __syncthreads();
    if (t == 0) out[0] = r[0] + r[1] + r[2] + r[3];
}

// old fp32 VALU edge GEMM (fallback only)
#define K1_BL 4
#define K1_BM 128
#define K1_PP 4
__global__ __launch_bounds__(512) void k1_edge(const float* __restrict__ Jg,
                                               const float* __restrict__ msa_k,
                                               float* __restrict__ Hc) {
    const int m0 = blockIdx.x * K1_BM;
    const int l0 = blockIdx.y * K1_BL;
    const int tid = threadIdx.x;
    const int mq = tid & 31;
    const int nq = tid >> 5;
    __shared__ float Jl[K1_PP][AA_][96];
    float acc[6][4];
#pragma unroll
    for (int j = 0; j < 6; ++j)
#pragma unroll
        for (int i = 0; i < 4; ++i) acc[j][i] = 0.f;
    const int nj = (nq < 4) ? 6 : 5;
    for (int p0 = 0; p0 < LL_; p0 += K1_PP) {
        __syncthreads();
        for (int idx = tid; idx < K1_BL * K1_PP * 441; idx += 512) {
            const int pair = idx / 441;
            const int f = idx - pair * 441;
            const int ll = pair >> 2;
            const int pp = pair & 3;
            const int c = f / 21;
            const int a = f - c * 21;
            Jl[pp][a][ll * 21 + c] =
                Jg[(size_t)(l0 + ll) * (LL_ * AA_ * AA_) + (size_t)(p0 + pp) * 441 + f];
        }
        __syncthreads();
#pragma unroll
        for (int pp = 0; pp < K1_PP; ++pp) {
#pragma unroll 7
            for (int a = 0; a < AA_; ++a) {
                const int k = (p0 + pp) * AA_ + a;
                const float4 av = *(const float4*)(msa_k + (size_t)k * MM_ + m0 + (mq << 2));
#pragma unroll
                for (int j = 0; j < 6; ++j) {
                    const float b = Jl[pp][a][nq + 16 * j];
                    acc[j][0] = fmaf(av.x, b, acc[j][0]);
                    acc[j][1] = fmaf(av.y, b, acc[j][1]);
                    acc[j][2] = fmaf(av.z, b, acc[j][2]);
                    acc[j][3] = fmaf(av.w, b, acc[j][3]);
                }
            }
        }
    }
    for (int j = 0; j < nj; ++j) {
        const int n = nq + 16 * j;
        const int ll = n / 21;
        const int c = n - ll * 21;
        const int l = l0 + ll;
#pragma unroll
        for (int i = 0; i < 4; ++i) {
            const int m = m0 + (mq << 2) + i;
            Hc[((size_t)m * LL_ + l) * AA_ + c] = acc[j][i];
        }
    }
}

__global__ __launch_bounds__(512) void k2_node(const float* __restrict__ MSA,
                                               const float* __restrict__ hvec,
                                               const float* __restrict__ Hc,
                                               float* __restrict__ logp,
                                               float* __restrict__ out) {
    const int l = blockIdx.x;
    const int m = threadIdx.x;
    __shared__ float hl[AA_];
    if (m < AA_) hl[m] = hvec[l * AA_ + m];
    __syncthreads();
    const float* msa = MSA + ((size_t)l * MM_ + m) * AA_;
    const float* hc = Hc + ((size_t)m * LL_ + l) * AA_;
    float msav[AA_], hcv[AA_];
#pragma unroll
    for (int a = 0; a < AA_; ++a) { msav[a] = msa[a]; hcv[a] = hc[a]; }
    float nodewt = 0.f, edgewt = 0.f;
#pragma unroll
    for (int a = 0; a < AA_; ++a) {
        nodewt = fmaf(msav[a], hl[a], nodewt);
        edgewt = fmaf(msav[a], hcv[a], edgewt);
    }
    float hd[CC_];
    float mx = -1e30f;
#pragma unroll
    for (int c = 0; c < CC_; ++c) {
        hd[c] = (hl[c] - nodewt) + (hcv[c] - edgewt);
        mx = fmaxf(mx, -hd[c]);
    }
    float s = 0.f;
#pragma unroll
    for (int c = 0; c < CC_; ++c) s += expf(-hd[c] - mx);
    const float lse = mx + logf(s);
    float lpsum = 0.f;
#pragma unroll
    for (int c = 0; c < CC_; ++c) lpsum = fmaf(-hd[c] - lse, msav[c], lpsum);
    logp[l * MM_ + m] = lpsum;
    if (m == 0) {
#pragma unroll
        for (int c = 0; c < CC_; ++c) out[l * CC_ + c] = hd[c];
    }
}

__global__ __launch_bounds__(256) void k3_sim(const float* __restrict__ msa_k,
                                              const float* __restrict__ lw,
                                              float* __restrict__ S) {
    const int m0 = blockIdx.x * 64;
    const int n0 = blockIdx.y * 64;
    const int l0 = blockIdx.z * 32;
    const int tid = threadIdx.x;
    const int tx = tid & 15;
    const int ty = tid >> 4;
    __shared__ __align__(16) float As[21][64];
    __shared__ __align__(16) float Bs[21][64];
    float acc[4][4];
#pragma unroll
    for (int i = 0; i < 4; ++i)
#pragma unroll
        for (int j = 0; j < 4; ++j) acc[i][j] = 0.f;
    for (int l = l0; l < l0 + 32; ++l) {
        __syncthreads();
        const float lwv = lw[l];
        for (int idx = tid; idx < 21 * 64; idx += 256) {
            const int kk = idx >> 6, mm = idx & 63;
            const size_t row = (size_t)(l * 21 + kk) * MM_;
            As[kk][mm] = msa_k[row + m0 + mm];
            Bs[kk][mm] = msa_k[row + n0 + mm] * lwv;
        }
        __syncthreads();
#pragma unroll 7
        for (int kk = 0; kk < 21; ++kk) {
            const float4 a4 = *(const float4*)&As[kk][tx * 4];
            const float4 b4 = *(const float4*)&Bs[kk][ty * 4];
            const float av[4] = {a4.x, a4.y, a4.z, a4.w};
            const float bv[4] = {b4.x, b4.y, b4.z, b4.w};
#pragma unroll
            for (int i = 0; i < 4; ++i)
#pragma unroll
                for (int j = 0; j < 4; ++j)
                    acc[i][j] = fmaf(av[i], bv[j], acc[i][j]);
        }
    }
#pragma unroll
    for (int i = 0; i < 4; ++i)
#pragma unroll
        for (int j = 0; j < 4; ++j)
            atomicAdd(&S[(size_t)(m0 + tx * 4 + i) * MM_ + n0 + ty * 4 + j], acc[i][j]);
}

__global__ __launch_bounds__(64) void k4_denom(const float* __restrict__ S,
                                               const float* __restrict__ lwsum_p,
                                               float* __restrict__ denom) {
    const int m = blockIdx.x * 64 + threadIdx.x;
    const float inv = 1.0f / lwsum_p[0];
    float s = 0.f;
    for (int n = 0; n < MM_; ++n) {
        const float sim = S[(size_t)n * MM_ + m] * inv;
        s += 1.0f / (1.0f + expf(-SIM_K * (sim - SIM_MID)));
    }
    denom[m] = s;
}

__global__ __launch_bounds__(512) void k5_final(const float* __restrict__ logp,
                                                const float* __restrict__ lw,
                                                const float* __restrict__ denom,
                                                const float* __restrict__ dw,
                                                float* __restrict__ out) {
    const int m = threadIdx.x;
    float lp = 0.f;
    for (int l = 0; l < LL_; ++l) lp = fmaf(logp[l * MM_ + m], lw[l], lp);
    const float sw = dw[m] / denom[m];
    float a = sw * lp, b = sw;
#pragma unroll
    for (int off = 32; off; off >>= 1) {
        a += __shfl_down(a, off, 64);
        b += __shfl_down(b, off, 64);
    }
    __shared__ float ra[8], rb[8];
    if ((m & 63) == 0) { ra[m >> 6] = a; rb[m >> 6] = b; }
    __syncthreads();
    if (m == 0) {
        float sa = 0.f, sb = 0.f;
#pragma unroll
        for (int w = 0; w < 8; ++w) { sa += ra[w]; sb += rb[w]; }
        out[5120] = sa / sb;
    }
}

extern "C" void kernel_launch(void* const* d_in, const int* in_sizes, int n_in,
                              void* d_out, int out_size, void* d_ws, size_t ws_size,
                              hipStream_t stream) {
    const float* MSA = (const float*)d_in[0];
    const float* h   = (const float*)d_in[1];
    const float* J   = (const float*)d_in[2];
    const float* lw  = (const float*)d_in[3];
    const float* dw  = (const float*)d_in[4];
    float* out = (float*)d_out;

    if (ws_size >= WS_NEED) {
        char* wsb = (char*)d_ws;
        unsigned short* Jt_hi = (unsigned short*)(wsb + B_JTHI);
        unsigned short* Jt_lo = (unsigned short*)(wsb + B_JTLO);
        unsigned short* Ah    = (unsigned short*)(wsb + B_AH);
        unsigned short* Al    = (unsigned short*)(wsb + B_AL);
        float* Hc    = (float*)(wsb + B_HC);
        float* msa_k = (float*)(wsb + B_MSAK);
        float* logp  = (float*)(wsb + B_LOGP);
        float* S     = (float*)(wsb + B_S);
        float* denom = (float*)(wsb + B_DENOM);
        float* lwsum = (float*)(wsb + B_LWSUM);

        kT_jt<<<dim3(LL_, 8), 256, 0, stream>>>(J, Jt_hi, Jt_lo);
        kA_msa<<<dim3(32, 8), 512, 0, stream>>>(MSA, Ah, Al);
        k0_transpose<<<dim3(LL_, MM_ / 256), 256, 0, stream>>>(MSA, msa_k);
        k_lwsum<<<1, 256, 0, stream>>>(lw, lwsum);
        // zero S and Hc (ws is poisoned each call; both are atomicAdd targets)
        hipMemsetAsync(S, 0, (size_t)MM_ * MM_ * sizeof(float), stream);
        hipMemsetAsync(Hc, 0, (size_t)MM_ * KK_ * sizeof(float), stream);
        k1_mfma<<<dim3(4, 64, 2), 512, 0, stream>>>(Jt_hi, Jt_lo, Ah, Al, Hc);
        k3_sim<<<dim3(8, 8, 8), 256, 0, stream>>>(msa_k, lw, S);
        k2_node<<<dim3(LL_), 512, 0, stream>>>(MSA, h, Hc, logp, out);
        k4_denom<<<dim3(MM_ / 64), 64, 0, stream>>>(S, lwsum, denom);
        k5_final<<<1, 512, 0, stream>>>(logp, lw, denom, dw, out);
    } else {
        float* ws = (float*)d_ws;
        float* msa_k = ws + OFF_MSAK;
        float* Hc    = ws + OFF_HC;
        float* logp  = ws + OFF_LOGP;
        float* S     = ws + OFF_S;
        float* denom = ws + OFF_DENOM;
        float* lwsum = ws + OFF_LWSUM;
        k0_transpose<<<dim3(LL_, MM_ / 256), 256, 0, stream>>>(MSA, msa_k);
        k_lwsum<<<1, 256, 0, stream>>>(lw, lwsum);
        hipMemsetAsync(S, 0, (size_t)MM_ * MM_ * sizeof(float), stream);
        k1_edge<<<dim3(MM_ / K1_BM, LL_ / K1_BL), 512, 0, stream>>>(J, msa_k, Hc);
        k3_sim<<<dim3(8, 8, 8), 256, 0, stream>>>(msa_k, lw, S);
        k2_node<<<dim3(LL_), 512, 0, stream>>>(MSA, h, Hc, logp, out);
        k4_denom<<<dim3(MM_ / 64), 64, 0, stream>>>(S, lwsum, denom);
        k5_final<<<1, 512, 0, stream>>>(logp, lw, denom, dw, out);
    }
}